// Round 17
// baseline (215.973 us; speedup 1.0000x reference)
//
#include <hip/hip_runtime.h>
#include <math.h>

typedef unsigned int uint;
typedef unsigned short ushort;
typedef short s16x8 __attribute__((ext_vector_type(8)));
typedef float f32x4 __attribute__((ext_vector_type(4)));

#define PIX 16384
#define EPSF 1e-5f

__device__ __forceinline__ ushort f2bf(float f) {
  union { float f; uint u; } v; v.f = f;
  uint u = v.u;
  uint r = (u + 0x7FFFu + ((u >> 16) & 1u)) >> 16;
  return (ushort)r;
}
__device__ __forceinline__ float bf2f(ushort h) {
  union { uint u; float f; } v; v.u = ((uint)h) << 16;
  return v.f;
}
__device__ __forceinline__ uint pk2(float a, float b) {
  return (uint)f2bf(a) | ((uint)f2bf(b) << 16);
}
__device__ __forceinline__ float frcp(float x) { return __builtin_amdgcn_rcpf(x); }
__device__ __forceinline__ float fsigmoid(float v) { return frcp(1.f + __expf(-v)); }
__device__ __forceinline__ float ftanh(float v) { return 1.f - 2.f * frcp(__expf(2.f * v) + 1.f); }

union Frag { uint4 u4; uint u[4]; s16x8 s; };

// ---------------- merged weight fragment prep (+ folded-LN S/Tb vectors) ----------------
// frag (mt, ks): lane l elem j = W[mt*16 + (l&15)][ks*32 + (l>>4)*8 + j]
// FWq columns pre-scaled by ln_g. Tail threads (idx>=19456) compute Sarr/Tbarr.
__global__ void k_prep(const float* __restrict__ Wp, const float* __restrict__ Wq,
                       const float* __restrict__ Wo, const float* __restrict__ Wg,
                       const float* __restrict__ ln_g, const float* __restrict__ ln_b,
                       const float* __restrict__ bqkv,
                       ushort* __restrict__ FWp, ushort* __restrict__ FWq,
                       ushort* __restrict__ FWo, ushort* __restrict__ FWg,
                       float* __restrict__ Sarr, float* __restrict__ Tbarr) {
  int idx = blockIdx.x * 256 + threadIdx.x;   // [0, 19968)
  if (idx >= 19456) {
    int o = idx - 19456;
    if (o >= 384) return;
    float S = 0.f, T = 0.f;
    const float* wr = Wq + (size_t)o * 128;
    for (int i = 0; i < 128; i++) {
      float wv = wr[i];
      S = fmaf(wv, ln_g[i], S);
      T = fmaf(wv, ln_b[i], T);
    }
    Sarr[o] = S;
    Tbarr[o] = T + bqkv[o];
    return;
  }
  const float* W; ushort* F; int KS, ldw, rel; bool scale = false;
  if (idx < 3072)       { W = Wp; F = FWp; KS = 6; ldw = 192; rel = idx; }
  else if (idx < 9216)  { W = Wq; F = FWq; KS = 4; ldw = 128; rel = idx - 3072; scale = true; }
  else if (idx < 11264) { W = Wo; F = FWo; KS = 4; ldw = 128; rel = idx - 9216; }
  else                  { W = Wg; F = FWg; KS = 4; ldw = 128; rel = idx - 11264; }
  int l = rel & 63, rest = rel >> 6;
  int ks = rest % KS, mt = rest / KS;
  int col = ks * 32 + (l >> 4) * 8;
  const float* src = W + (size_t)(mt * 16 + (l & 15)) * ldw + col;
  float g[8] = {1.f, 1.f, 1.f, 1.f, 1.f, 1.f, 1.f, 1.f};
  if (scale) {
    #pragma unroll
    for (int j = 0; j < 8; j++) g[j] = ln_g[col + j];
  }
  uint4 v;
  v.x = pk2(src[0] * g[0], src[1] * g[1]);
  v.y = pk2(src[2] * g[2], src[3] * g[3]);
  v.z = pk2(src[4] * g[4], src[5] * g[5]);
  v.w = pk2(src[6] * g[6], src[7] * g[7]);
  *reinterpret_cast<uint4*>(F + (size_t)rel * 8) = v;
}

// ---------------- fused proj + (folded LN) + window MHSA + Wo (+GN stats) ----------------
// (round-10 validated structure; frcp softmax; s_setprio around MFMA clusters)
__global__ __launch_bounds__(256, 3) void k_attn(
    const float* __restrict__ x, const float* __restrict__ h,
    const ushort* __restrict__ FWp, const float* __restrict__ bproj,
    const ushort* __restrict__ FWq, const float* __restrict__ Sarr,
    const float* __restrict__ Tbarr,
    const ushort* __restrict__ FWoT, const float* __restrict__ bo,
    ushort* __restrict__ attn_map, float* __restrict__ stA_raw)
{
  __shared__ __align__(16) char LM[51200];
  __shared__ float sSum[64], sSum2[64];
  __shared__ float sStat[16];

  const int t = threadIdx.x;
  const int bid = blockIdx.x;
  const int b = bid >> 8, wh = (bid >> 3) & 31, ww0 = bid & 7;
  const int w = t >> 6, l = t & 63, q = l >> 4, r16 = l & 15;

  uint* sInP = (uint*)LM;            // [96][68] dwords (26112 B)
  ushort* sXn = (ushort*)LM;         // [64][136]

  if (t < 64) { sSum[t] = 0.f; sSum2[t] = 0.f; }
  if (t < 16) sStat[t] = 0.f;

  // ---- phase 0: stage concat(x,h) -> sInP[chp][col], col = window*16 + token ----
  {
    const float* xb = x + (size_t)b * 64 * PIX;
    const float* hb = h + (size_t)b * 128 * PIX;
    #pragma unroll
    for (int it = 0; it < 6; it++) {
      int item = it * 256 + t;                 // [0,1536)
      int wv = item & 3, r = (item >> 2) & 3, chp = item >> 4;
      int ch0 = chp * 2;
      int gpix = (wh * 4 + r) * 128 + ww0 * 16 + wv * 4;
      float4 a, c2;
      if (ch0 < 64) {
        a  = *reinterpret_cast<const float4*>(xb + (size_t)ch0 * PIX + gpix);
        c2 = *reinterpret_cast<const float4*>(xb + (size_t)(ch0 + 1) * PIX + gpix);
      } else {
        a  = *reinterpret_cast<const float4*>(hb + (size_t)(ch0 - 64) * PIX + gpix);
        c2 = *reinterpret_cast<const float4*>(hb + (size_t)(ch0 - 63) * PIX + gpix);
      }
      uint4 pkd;
      pkd.x = pk2(a.x, c2.x); pkd.y = pk2(a.y, c2.y);
      pkd.z = pk2(a.z, c2.z); pkd.w = pk2(a.w, c2.w);
      *reinterpret_cast<uint4*>(sInP + chp * 68 + wv * 16 + r * 4) = pkd;
    }
  }
  __syncthreads();   // B1

  // ---- phase 1: proj MFMA. wave w owns mt in {w, w+4}; nt = window 0..3 ----
  f32x4 acc1[2][4];
  {
    #pragma unroll
    for (int mi = 0; mi < 2; mi++)
      #pragma unroll
      for (int nt = 0; nt < 4; nt++) acc1[mi][nt] = (f32x4){0.f, 0.f, 0.f, 0.f};
    __builtin_amdgcn_s_setprio(1);
    for (int ks = 0; ks < 6; ks++) {
      Frag bf[4];
      #pragma unroll
      for (int nt = 0; nt < 4; nt++)
        #pragma unroll
        for (int s = 0; s < 4; s++)
          bf[nt].u[s] = sInP[(ks * 16 + q * 4 + s) * 68 + nt * 16 + r16];
      #pragma unroll
      for (int mi = 0; mi < 2; mi++) {
        Frag af;
        af.u4 = *reinterpret_cast<const uint4*>(FWp + (((w + mi * 4) * 6 + ks) * 64 + l) * 8);
        #pragma unroll
        for (int nt = 0; nt < 4; nt++)
          acc1[mi][nt] = __builtin_amdgcn_mfma_f32_16x16x32_bf16(af.s, bf[nt].s, acc1[mi][nt], 0, 0, 0);
      }
    }
    __builtin_amdgcn_s_setprio(0);
  }
  __syncthreads();   // B2: all sInP reads done; sXn overlays

  // ---- phase 1b: bias, pack raw p -> sXn, per-token LN stats (fp32) ----
  {
    float pst[4] = {0.f, 0.f, 0.f, 0.f}, pst2[4] = {0.f, 0.f, 0.f, 0.f};
    #pragma unroll
    for (int mi = 0; mi < 2; mi++) {
      int o0 = (w + mi * 4) * 16 + q * 4;
      const float4 bv = *reinterpret_cast<const float4*>(bproj + o0);
      #pragma unroll
      for (int nt = 0; nt < 4; nt++) {
        float v0 = acc1[mi][nt][0] + bv.x, v1 = acc1[mi][nt][1] + bv.y;
        float v2 = acc1[mi][nt][2] + bv.z, v3 = acc1[mi][nt][3] + bv.w;
        uint2 pk; pk.x = pk2(v0, v1); pk.y = pk2(v2, v3);
        *reinterpret_cast<uint2*>(sXn + (nt * 16 + r16) * 136 + o0) = pk;
        pst[nt]  += v0 + v1 + v2 + v3;
        pst2[nt] += v0 * v0 + v1 * v1 + v2 * v2 + v3 * v3;
      }
    }
    #pragma unroll
    for (int nt = 0; nt < 4; nt++) {
      float s = pst[nt], s2 = pst2[nt];
      s  += __shfl_xor(s, 16);  s  += __shfl_xor(s, 32);
      s2 += __shfl_xor(s2, 16); s2 += __shfl_xor(s2, 32);
      if (q == 0) {
        atomicAdd(&sSum[nt * 16 + r16], s);
        atomicAdd(&sSum2[nt * 16 + r16], s2);
      }
    }
  }
  __syncthreads();   // B3: sXn + stats ready

  // ---- phase 2: hoist xn frags; QK GEMM -> slices; V GEMM held in regs ----
  float rstd_[4], mr_[4];
  f32x4 accV[2][4];
  {
    Frag bfh[4][4];   // [ks][nt] — all sXn reads happen here
    #pragma unroll
    for (int ks = 0; ks < 4; ks++)
      #pragma unroll
      for (int nt = 0; nt < 4; nt++)
        bfh[ks][nt].u4 = *reinterpret_cast<const uint4*>(sXn + (nt * 16 + r16) * 136 + ks * 32 + q * 8);

    #pragma unroll
    for (int nt = 0; nt < 4; nt++) {
      int tok = nt * 16 + r16;
      float mu = sSum[tok] * 0.0078125f;
      float var = sSum2[tok] * 0.0078125f - mu * mu;
      rstd_[nt] = rsqrtf(var + EPSF);
      mr_[nt] = -mu * rstd_[nt];
    }

    ushort* sQKu = (ushort*)(LM + 17408);
    #pragma unroll
    for (int mi = 0; mi < 4; mi++) {        // Q,K tiles: mt = w + mi*4 < 16
      int mt = w + mi * 4;
      f32x4 accq[4];
      #pragma unroll
      for (int nt = 0; nt < 4; nt++) accq[nt] = (f32x4){0.f, 0.f, 0.f, 0.f};
      __builtin_amdgcn_s_setprio(1);
      #pragma unroll
      for (int ks = 0; ks < 4; ks++) {
        Frag af;
        af.u4 = *reinterpret_cast<const uint4*>(FWq + ((mt * 4 + ks) * 64 + l) * 8);
        #pragma unroll
        for (int nt = 0; nt < 4; nt++)
          accq[nt] = __builtin_amdgcn_mfma_f32_16x16x32_bf16(af.s, bfh[ks][nt].s, accq[nt], 0, 0, 0);
      }
      __builtin_amdgcn_s_setprio(0);
      int oo = mt * 16 + q * 4;
      const float4 S4  = *reinterpret_cast<const float4*>(Sarr + oo);
      const float4 Tb4 = *reinterpret_cast<const float4*>(Tbarr + oo);
      #pragma unroll
      for (int nt = 0; nt < 4; nt++) {
        float v0 = fmaf(rstd_[nt], accq[nt][0], fmaf(mr_[nt], S4.x, Tb4.x));
        float v1 = fmaf(rstd_[nt], accq[nt][1], fmaf(mr_[nt], S4.y, Tb4.y));
        float v2 = fmaf(rstd_[nt], accq[nt][2], fmaf(mr_[nt], S4.z, Tb4.z));
        float v3 = fmaf(rstd_[nt], accq[nt][3], fmaf(mr_[nt], S4.w, Tb4.w));
        uint2 pk; pk.x = pk2(v0, v1); pk.y = pk2(v2, v3);
        *reinterpret_cast<uint2*>(sQKu + nt * 4224 + r16 * 264 + oo) = pk;
      }
    }
    __builtin_amdgcn_s_setprio(1);
    #pragma unroll
    for (int mi = 0; mi < 2; mi++) {        // V tiles: mt = w+16, w+20
      int mt = w + 16 + mi * 4;
      #pragma unroll
      for (int nt = 0; nt < 4; nt++) accV[mi][nt] = (f32x4){0.f, 0.f, 0.f, 0.f};
      #pragma unroll
      for (int ks = 0; ks < 4; ks++) {
        Frag af;
        af.u4 = *reinterpret_cast<const uint4*>(FWq + ((mt * 4 + ks) * 64 + l) * 8);
        #pragma unroll
        for (int nt = 0; nt < 4; nt++)
          accV[mi][nt] = __builtin_amdgcn_mfma_f32_16x16x32_bf16(af.s, bfh[ks][nt].s, accV[mi][nt], 0, 0, 0);
      }
    }
    __builtin_amdgcn_s_setprio(0);
  }
  __syncthreads();   // B4: all waves' sXn reads drained; R0 free for V

  // ---- phase 2b: V epilogue -> R0 [0,16384) ----
  {
    ushort* sVu = (ushort*)LM;
    #pragma unroll
    for (int mi = 0; mi < 2; mi++) {
      int mt = w + 16 + mi * 4;
      int oo = mt * 16 + q * 4;
      const float4 S4  = *reinterpret_cast<const float4*>(Sarr + oo);
      const float4 Tb4 = *reinterpret_cast<const float4*>(Tbarr + oo);
      #pragma unroll
      for (int nt = 0; nt < 4; nt++) {
        float v0 = fmaf(rstd_[nt], accV[mi][nt][0], fmaf(mr_[nt], S4.x, Tb4.x));
        float v1 = fmaf(rstd_[nt], accV[mi][nt][1], fmaf(mr_[nt], S4.y, Tb4.y));
        float v2 = fmaf(rstd_[nt], accV[mi][nt][2], fmaf(mr_[nt], S4.z, Tb4.z));
        float v3 = fmaf(rstd_[nt], accV[mi][nt][3], fmaf(mr_[nt], S4.w, Tb4.w));
        ushort* vd = sVu + nt * 2048 + (oo - 256) * 16 + r16;
        vd[0] = f2bf(v0); vd[16] = f2bf(v1); vd[32] = f2bf(v2); vd[48] = f2bf(v3);
      }
    }
  }
  __syncthreads();   // B4b: V visible to all waves

  // ---- phase 3: scores + softmax + PV, wave = window w ----
  {
    const float scale = 0.17677669529663687f;
    ushort* sQKw = (ushort*)(LM + 17408 + w * 8448);
    ushort* sPw  = sQKw;
    Frag af4[4], bf4[4];
    #pragma unroll
    for (int hd = 0; hd < 4; hd++) {
      af4[hd].u4 = *reinterpret_cast<const uint4*>(sQKw + r16 * 264 + hd * 32 + q * 8);
      bf4[hd].u4 = *reinterpret_cast<const uint4*>(sQKw + r16 * 264 + 128 + hd * 32 + q * 8);
    }
    #pragma unroll
    for (int hd = 0; hd < 4; hd++) {
      if (l < 32) {
        int row = l >> 1, hz = l & 1;
        uint4 z = {0u, 0u, 0u, 0u};
        *reinterpret_cast<uint4*>(sPw + hd * 512 + row * 32 + 16 + hz * 8) = z;
      }
    }
    f32x4 sc[4];
    __builtin_amdgcn_s_setprio(1);
    #pragma unroll
    for (int hd = 0; hd < 4; hd++) {
      f32x4 z4 = (f32x4){0.f, 0.f, 0.f, 0.f};
      sc[hd] = __builtin_amdgcn_mfma_f32_16x16x32_bf16(af4[hd].s, bf4[hd].s, z4, 0, 0, 0);
    }
    __builtin_amdgcn_s_setprio(0);
    #pragma unroll
    for (int hd = 0; hd < 4; hd++) {
      ushort* pd = sPw + hd * 512 + (q * 4) * 32 + r16;
      #pragma unroll
      for (int r = 0; r < 4; r++) {
        float sv = sc[hd][r] * scale;
        float mx = sv;
        mx = fmaxf(mx, __shfl_xor(mx, 1));
        mx = fmaxf(mx, __shfl_xor(mx, 2));
        mx = fmaxf(mx, __shfl_xor(mx, 4));
        mx = fmaxf(mx, __shfl_xor(mx, 8));
        float e = __expf(sv - mx);
        float sm = e;
        sm += __shfl_xor(sm, 1); sm += __shfl_xor(sm, 2);
        sm += __shfl_xor(sm, 4); sm += __shfl_xor(sm, 8);
        pd[r * 32] = f2bf(e * frcp(sm));
      }
    }
    // PV -> sO at slice[4096,8448); V from R0
    ushort* sOw = sQKw + 2048;               // +4096 B
    ushort* sVw = (ushort*)LM + w * 2048;    // window w's V (4096 B)
    __builtin_amdgcn_s_setprio(1);
    #pragma unroll
    for (int hd = 0; hd < 4; hd++) {
      Frag pa;
      pa.u4 = *reinterpret_cast<const uint4*>(sPw + hd * 512 + r16 * 32 + q * 8);
      #pragma unroll
      for (int nt2 = 0; nt2 < 2; nt2++) {
        int ch = hd * 32 + nt2 * 16 + r16;
        int off = (q < 2) ? q * 8 : 0;
        Frag vf;
        vf.u4 = *reinterpret_cast<const uint4*>(sVw + ch * 16 + off);
        f32x4 z4 = (f32x4){0.f, 0.f, 0.f, 0.f};
        f32x4 o4 = __builtin_amdgcn_mfma_f32_16x16x32_bf16(pa.s, vf.s, z4, 0, 0, 0);
        ushort* od = sOw + (q * 4) * 136 + ch;
        od[0] = f2bf(o4[0]); od[136] = f2bf(o4[1]);
        od[272] = f2bf(o4[2]); od[408] = f2bf(o4[3]);
      }
    }
    __builtin_amdgcn_s_setprio(0);
  }
  __syncthreads();   // B5: all sO ready; R0 (V) dead -> sFin

  // ---- phase 4: Wo MFMA. wave w owns ntg in {w, w+4}; nt = window ----
  {
    ushort* sFinu = (ushort*)LM;
    Frag a4[4][4];
    #pragma unroll
    for (int nt = 0; nt < 4; nt++) {
      ushort* sOnt = (ushort*)(LM + 17408 + nt * 8448 + 4096);
      #pragma unroll
      for (int ks = 0; ks < 4; ks++)
        a4[nt][ks].u4 = *reinterpret_cast<const uint4*>(sOnt + r16 * 136 + ks * 32 + q * 8);
    }
    #pragma unroll
    for (int mi2 = 0; mi2 < 2; mi2++) {
      int ntg = w + mi2 * 4;
      f32x4 acw[4];
      #pragma unroll
      for (int nt = 0; nt < 4; nt++) acw[nt] = (f32x4){0.f, 0.f, 0.f, 0.f};
      __builtin_amdgcn_s_setprio(1);
      #pragma unroll
      for (int ks = 0; ks < 4; ks++) {
        Frag bfw;
        bfw.u4 = *reinterpret_cast<const uint4*>(FWoT + ((ntg * 4 + ks) * 64 + l) * 8);
        #pragma unroll
        for (int nt = 0; nt < 4; nt++)
          acw[nt] = __builtin_amdgcn_mfma_f32_16x16x32_bf16(a4[nt][ks].s, bfw.s, acw[nt], 0, 0, 0);
      }
      __builtin_amdgcn_s_setprio(0);
      int ch = ntg * 16 + r16;
      float bb = bo[ch];
      #pragma unroll
      for (int nt = 0; nt < 4; nt++) {
        uint2 pk;
        pk.x = pk2(acw[nt][0] + bb, acw[nt][1] + bb);
        pk.y = pk2(acw[nt][2] + bb, acw[nt][3] + bb);
        *reinterpret_cast<uint2*>(sFinu + nt * 2048 + ch * 16 + q * 4) = pk;
      }
    }
  }
  __syncthreads();   // B6

  // ---- phase 5: coalesced writeout (2 windows per 16B) + GN partial stats ----
  {
    ushort* sFinu = (ushort*)LM;
    #pragma unroll
    for (int it = 0; it < 4; it++) {
      int seg = it * 256 + t;            // [0,1024)
      int ch = seg >> 3, r = (seg >> 1) & 3, half = seg & 1;
      const ushort* f0 = sFinu + (half * 2    ) * 2048;
      const ushort* f1 = sFinu + (half * 2 + 1) * 2048;
      uint2 a  = *reinterpret_cast<const uint2*>(f0 + ch * 16 + r * 4);
      uint2 c2 = *reinterpret_cast<const uint2*>(f1 + ch * 16 + r * 4);
      uint4 val = {a.x, a.y, c2.x, c2.y};
      *reinterpret_cast<uint4*>(attn_map + (size_t)(b * 128 + ch) * PIX
                                + (wh * 4 + r) * 128 + ww0 * 16 + half * 8) = val;
      float sv = 0.f, sv2 = 0.f;
      uint uu[4] = {val.x, val.y, val.z, val.w};
      #pragma unroll
      for (int k2 = 0; k2 < 4; k2++) {
        float fv0 = bf2f((ushort)(uu[k2] & 0xFFFFu));
        float fv1 = bf2f((ushort)(uu[k2] >> 16));
        sv += fv0 + fv1; sv2 += fv0 * fv0 + fv1 * fv1;
      }
      sv  += __shfl_xor(sv, 1);  sv  += __shfl_xor(sv, 2);  sv  += __shfl_xor(sv, 4);
      sv2 += __shfl_xor(sv2, 1); sv2 += __shfl_xor(sv2, 2); sv2 += __shfl_xor(sv2, 4);
      if ((t & 7) == 0) {
        int g = ch >> 4;
        atomicAdd(&sStat[g * 2], sv);
        atomicAdd(&sStat[g * 2 + 1], sv2);
      }
    }
  }
  __syncthreads();
  if (t < 16) atomicAdd(&stA_raw[b * 16 + t], sStat[t]);
}

// ---------------- GN + gates MFMA + LSTM update (+stats for GN2) ----------------
// (round-10 v3; frcp transcendentals; setprio around GEMM)
__global__ __launch_bounds__(256, 4) void k_gates(
    const ushort* __restrict__ attn_map, const float* __restrict__ stA_raw,
    const float* __restrict__ gn_g, const float* __restrict__ gn_b,
    const ushort* __restrict__ FWg, const float* __restrict__ bgates,
    const float* __restrict__ c, float* __restrict__ cnext,
    ushort* __restrict__ tbuf, float* __restrict__ stB_raw)
{
  __shared__ uint sG2[32 * 66];     // [px][ch-pair dwords + 2 pad] = 8448 B
  __shared__ float sA[128], sB[128];
  __shared__ float sStat[16];
  const int t = threadIdx.x, bid = blockIdx.x;
  const int b = bid >> 9, p0 = (bid & 511) * 32;
  const int w = t >> 6, l = t & 63, q = l >> 4, r16 = l & 15;

  if (t < 128) {
    int g = t >> 4;
    const float invN = 1.f / 262144.f;
    float mu = stA_raw[b * 16 + g * 2] * invN;
    float var = stA_raw[b * 16 + g * 2 + 1] * invN - mu * mu;
    float rs = rsqrtf(var + EPSF);
    float A = rs * gn_g[t];
    sA[t] = A; sB[t] = gn_b[t] - mu * A;
  }
  if (t >= 240) sStat[t - 240] = 0.f;
  __syncthreads();

  // ---- staging: GN(attn) -> sG2[px][ch] (transposed) ----
  {
    int pr = t >> 2, px0 = (t & 3) * 8;
    int c0 = pr * 2;
    const ushort* ab = attn_map + (size_t)(b * 128 + c0) * PIX + p0 + px0;
    uint4 a0 = *reinterpret_cast<const uint4*>(ab);
    uint4 a1 = *reinterpret_cast<const uint4*>(ab + PIX);
    float A0 = sA[c0], B0 = sB[c0], A1 = sA[c0 + 1], B1 = sB[c0 + 1];
    uint u0[4] = {a0.x, a0.y, a0.z, a0.w};
    uint u1[4] = {a1.x, a1.y, a1.z, a1.w};
    #pragma unroll
    for (int j = 0; j < 4; j++) {
      float v0lo = bf2f((ushort)(u0[j] & 0xFFFFu)) * A0 + B0;
      float v0hi = bf2f((ushort)(u0[j] >> 16)) * A0 + B0;
      float v1lo = bf2f((ushort)(u1[j] & 0xFFFFu)) * A1 + B1;
      float v1hi = bf2f((ushort)(u1[j] >> 16)) * A1 + B1;
      sG2[(px0 + 2 * j) * 66 + pr]     = pk2(v0lo, v1lo);
      sG2[(px0 + 2 * j + 1) * 66 + pr] = pk2(v0hi, v1hi);
    }
  }

  // ---- prefetch c ----
  float4 cv[2][2];
  #pragma unroll
  for (int j = 0; j < 2; j++) {
    int ch = (w + 4 * j) * 16 + r16;
    const float* cb = c + (size_t)(b * 128 + ch) * PIX + p0 + q * 4;
    cv[j][0] = *reinterpret_cast<const float4*>(cb);
    cv[j][1] = *reinterpret_cast<const float4*>(cb + 16);
  }
  __syncthreads();

  // ---- gates GEMM: D[px][ch]; acc[gate][j][pxt], ch tile = w + 4j + 8*gate ----
  f32x4 acc[4][2][2];
  #pragma unroll
  for (int g2 = 0; g2 < 4; g2++)
    #pragma unroll
    for (int j = 0; j < 2; j++)
      #pragma unroll
      for (int pxt = 0; pxt < 2; pxt++) acc[g2][j][pxt] = (f32x4){0.f, 0.f, 0.f, 0.f};

  const ushort* sGu = (const ushort*)sG2;
  __builtin_amdgcn_s_setprio(1);
  for (int ks = 0; ks < 4; ks++) {
    Frag af[2];
    #pragma unroll
    for (int pxt = 0; pxt < 2; pxt++)
      af[pxt].u4 = *reinterpret_cast<const uint4*>(sGu + (pxt * 16 + r16) * 132 + ks * 32 + q * 8);
    #pragma unroll
    for (int g2 = 0; g2 < 4; g2++) {
      #pragma unroll
      for (int j = 0; j < 2; j++) {
        int ct = w + 4 * j + 8 * g2;
        Frag bfw;
        bfw.u4 = *reinterpret_cast<const uint4*>(FWg + ((ct * 4 + ks) * 64 + l) * 8);
        #pragma unroll
        for (int pxt = 0; pxt < 2; pxt++)
          acc[g2][j][pxt] = __builtin_amdgcn_mfma_f32_16x16x32_bf16(af[pxt].s, bfw.s, acc[g2][j][pxt], 0, 0, 0);
      }
    }
  }
  __builtin_amdgcn_s_setprio(0);

  // ---- LSTM epilogue: vectorized c/cnext/tbuf ----
  float gs[2] = {0.f, 0.f}, gs2[2] = {0.f, 0.f};
  #pragma unroll
  for (int j = 0; j < 2; j++) {
    int ch = (w + 4 * j) * 16 + r16;
    float bi = bgates[ch], bff = bgates[128 + ch], bog = bgates[256 + ch], bgg = bgates[384 + ch];
    #pragma unroll
    for (int pxt = 0; pxt < 2; pxt++) {
      size_t gbase = (size_t)(b * 128 + ch) * PIX + p0 + pxt * 16 + q * 4;
      const float cc[4] = {cv[j][pxt].x, cv[j][pxt].y, cv[j][pxt].z, cv[j][pxt].w};
      float cn[4], tv[4];
      #pragma unroll
      for (int r = 0; r < 4; r++) {
        float ig = fsigmoid(acc[0][j][pxt][r] + bi);
        float fg = fsigmoid(acc[1][j][pxt][r] + bff);
        float og = fsigmoid(acc[2][j][pxt][r] + bog);
        float gg = ftanh   (acc[3][j][pxt][r] + bgg);
        cn[r] = fg * cc[r] + ig * gg;
        tv[r] = og * ftanh(cn[r]);
        gs[j] += tv[r]; gs2[j] += tv[r] * tv[r];
      }
      float4 cno = {cn[0], cn[1], cn[2], cn[3]};
      *reinterpret_cast<float4*>(cnext + gbase) = cno;
      uint2 tpk;
      tpk.x = pk2(tv[0], tv[1]); tpk.y = pk2(tv[2], tv[3]);
      *reinterpret_cast<uint2*>(tbuf + gbase) = tpk;
    }
  }
  #pragma unroll
  for (int j = 0; j < 2; j++) {
    float s = gs[j], s2 = gs2[j];
    s += __shfl_xor(s, 1); s += __shfl_xor(s, 2); s += __shfl_xor(s, 4);
    s += __shfl_xor(s, 8); s += __shfl_xor(s, 16); s += __shfl_xor(s, 32);
    s2 += __shfl_xor(s2, 1); s2 += __shfl_xor(s2, 2); s2 += __shfl_xor(s2, 4);
    s2 += __shfl_xor(s2, 8); s2 += __shfl_xor(s2, 16); s2 += __shfl_xor(s2, 32);
    if (l == 0) {
      int g = w + 4 * j;
      atomicAdd(&sStat[g * 2], s);
      atomicAdd(&sStat[g * 2 + 1], s2);
    }
  }
  __syncthreads();
  if (t < 16) atomicAdd(&stB_raw[b * 16 + t], sStat[t]);
}

// ---------------- hnext = GN2(tbuf), inline stats finalize ----------------
__global__ __launch_bounds__(256) void k_gnout(
    const ushort* __restrict__ tbuf, const float* __restrict__ stB_raw,
    const float* __restrict__ gn_g, const float* __restrict__ gn_b,
    float* __restrict__ hnext)
{
  size_t idx = ((size_t)blockIdx.x * 256 + threadIdx.x) * 8;
  if (idx >= (size_t)16777216) return;
  int chrow = (int)(idx >> 14);
  int b = chrow >> 7, ch = chrow & 127, g = ch >> 4;
  const float invN = 1.f / 262144.f;
  float mu = stB_raw[b * 16 + g * 2] * invN;
  float var = stB_raw[b * 16 + g * 2 + 1] * invN - mu * mu;
  float rstd = rsqrtf(var + EPSF);
  float A = gn_g[ch] * rstd, Bv = gn_b[ch] - mu * A;
  uint4 u = *reinterpret_cast<const uint4*>(tbuf + idx);
  float4 o0, o1;
  o0.x = bf2f((ushort)(u.x & 0xFFFFu)) * A + Bv;
  o0.y = bf2f((ushort)(u.x >> 16)) * A + Bv;
  o0.z = bf2f((ushort)(u.y & 0xFFFFu)) * A + Bv;
  o0.w = bf2f((ushort)(u.y >> 16)) * A + Bv;
  o1.x = bf2f((ushort)(u.z & 0xFFFFu)) * A + Bv;
  o1.y = bf2f((ushort)(u.z >> 16)) * A + Bv;
  o1.z = bf2f((ushort)(u.w & 0xFFFFu)) * A + Bv;
  o1.w = bf2f((ushort)(u.w >> 16)) * A + Bv;
  *reinterpret_cast<float4*>(hnext + idx) = o0;
  *reinterpret_cast<float4*>(hnext + idx + 4) = o1;
}

extern "C" void kernel_launch(void* const* d_in, const int* in_sizes, int n_in,
                              void* d_out, int out_size, void* d_ws, size_t ws_size,
                              hipStream_t stream) {
  (void)in_sizes; (void)n_in; (void)out_size; (void)ws_size;
  const float* x      = (const float*)d_in[0];
  const float* h      = (const float*)d_in[1];
  const float* c      = (const float*)d_in[2];
  const float* Wproj  = (const float*)d_in[3];
  const float* bproj  = (const float*)d_in[4];
  const float* ln_g   = (const float*)d_in[5];
  const float* ln_b   = (const float*)d_in[6];
  const float* Wqkv   = (const float*)d_in[7];
  const float* bqkv   = (const float*)d_in[8];
  const float* Wo     = (const float*)d_in[9];
  const float* bo     = (const float*)d_in[10];
  const float* Wgates = (const float*)d_in[11];
  const float* bgates = (const float*)d_in[12];
  const float* gn_g   = (const float*)d_in[13];
  const float* gn_b   = (const float*)d_in[14];

  float* out = (float*)d_out;
  float* hnext = out;
  float* cnext = out + 16777216;

  char* W = (char*)d_ws;
  ushort* attn = (ushort*)W;                          // 32 MB bf16
  ushort* tbuf = (ushort*)(W + 33554432);             // 32 MB bf16
  size_t off = 67108864;
  ushort* FWp = (ushort*)(W + off); off += 49152;
  ushort* FWq = (ushort*)(W + off); off += 98304;
  ushort* FWo = (ushort*)(W + off); off += 32768;
  ushort* FWg = (ushort*)(W + off); off += 131072;
  float* stA_raw = (float*)(W + off); off += 512;
  float* stB_raw = (float*)(W + off); off += 512;
  float* Sarr    = (float*)(W + off); off += 1536;
  float* Tbarr   = (float*)(W + off); off += 1536;

  hipMemsetAsync(stA_raw, 0, 1024, stream);

  k_prep<<<78, 256, 0, stream>>>(Wproj, Wqkv, Wo, Wgates, ln_g, ln_b, bqkv,
                                 FWp, FWq, FWo, FWg, Sarr, Tbarr);

  k_attn<<<2048, 256, 0, stream>>>(x, h, FWp, bproj, FWq, Sarr, Tbarr,
                                   FWo, bo, attn, stA_raw);
  k_gates<<<4096, 256, 0, stream>>>(attn, stA_raw, gn_g, gn_b, FWg, bgates,
                                    c, cnext, tbuf, stB_raw);
  k_gnout<<<8192, 256, 0, stream>>>(tbuf, stB_raw, gn_g, gn_b, hnext);
}

// Round 18
// 196.341 us; speedup vs baseline: 1.1000x; 1.1000x over previous
//
#include <hip/hip_runtime.h>
#include <math.h>

typedef unsigned int uint;
typedef unsigned short ushort;
typedef short s16x8 __attribute__((ext_vector_type(8)));
typedef float f32x4 __attribute__((ext_vector_type(4)));

#define PIX 16384
#define EPSF 1e-5f

__device__ __forceinline__ ushort f2bf(float f) {
  union { float f; uint u; } v; v.f = f;
  uint u = v.u;
  uint r = (u + 0x7FFFu + ((u >> 16) & 1u)) >> 16;
  return (ushort)r;
}
__device__ __forceinline__ float bf2f(ushort h) {
  union { uint u; float f; } v; v.u = ((uint)h) << 16;
  return v.f;
}
__device__ __forceinline__ uint pk2(float a, float b) {
  return (uint)f2bf(a) | ((uint)f2bf(b) << 16);
}
__device__ __forceinline__ float frcp(float x) { return __builtin_amdgcn_rcpf(x); }
__device__ __forceinline__ float fsigmoid(float v) { return frcp(1.f + __expf(-v)); }
__device__ __forceinline__ float ftanh(float v) { return 1.f - 2.f * frcp(__expf(2.f * v) + 1.f); }

union Frag { uint4 u4; uint u[4]; s16x8 s; };

// ---------------- merged weight fragment prep (+ folded-LN S/Tb vectors) ----------------
// frag (mt, ks): lane l elem j = W[mt*16 + (l&15)][ks*32 + (l>>4)*8 + j]
// FWq columns pre-scaled by ln_g. Tail threads (idx>=19456) compute Sarr/Tbarr.
__global__ void k_prep(const float* __restrict__ Wp, const float* __restrict__ Wq,
                       const float* __restrict__ Wo, const float* __restrict__ Wg,
                       const float* __restrict__ ln_g, const float* __restrict__ ln_b,
                       const float* __restrict__ bqkv,
                       ushort* __restrict__ FWp, ushort* __restrict__ FWq,
                       ushort* __restrict__ FWo, ushort* __restrict__ FWg,
                       float* __restrict__ Sarr, float* __restrict__ Tbarr) {
  int idx = blockIdx.x * 256 + threadIdx.x;   // [0, 19968)
  if (idx >= 19456) {
    int o = idx - 19456;
    if (o >= 384) return;
    float S = 0.f, T = 0.f;
    const float* wr = Wq + (size_t)o * 128;
    for (int i = 0; i < 128; i++) {
      float wv = wr[i];
      S = fmaf(wv, ln_g[i], S);
      T = fmaf(wv, ln_b[i], T);
    }
    Sarr[o] = S;
    Tbarr[o] = T + bqkv[o];
    return;
  }
  const float* W; ushort* F; int KS, ldw, rel; bool scale = false;
  if (idx < 3072)       { W = Wp; F = FWp; KS = 6; ldw = 192; rel = idx; }
  else if (idx < 9216)  { W = Wq; F = FWq; KS = 4; ldw = 128; rel = idx - 3072; scale = true; }
  else if (idx < 11264) { W = Wo; F = FWo; KS = 4; ldw = 128; rel = idx - 9216; }
  else                  { W = Wg; F = FWg; KS = 4; ldw = 128; rel = idx - 11264; }
  int l = rel & 63, rest = rel >> 6;
  int ks = rest % KS, mt = rest / KS;
  int col = ks * 32 + (l >> 4) * 8;
  const float* src = W + (size_t)(mt * 16 + (l & 15)) * ldw + col;
  float g[8] = {1.f, 1.f, 1.f, 1.f, 1.f, 1.f, 1.f, 1.f};
  if (scale) {
    #pragma unroll
    for (int j = 0; j < 8; j++) g[j] = ln_g[col + j];
  }
  uint4 v;
  v.x = pk2(src[0] * g[0], src[1] * g[1]);
  v.y = pk2(src[2] * g[2], src[3] * g[3]);
  v.z = pk2(src[4] * g[4], src[5] * g[5]);
  v.w = pk2(src[6] * g[6], src[7] * g[7]);
  *reinterpret_cast<uint4*>(F + (size_t)rel * 8) = v;
}

// ---------------- fused proj + (folded LN) + window MHSA + Wo (+GN stats) ----------------
// (round-10 validated structure; frcp softmax; NO setprio — regressed in round 17)
__global__ __launch_bounds__(256, 3) void k_attn(
    const float* __restrict__ x, const float* __restrict__ h,
    const ushort* __restrict__ FWp, const float* __restrict__ bproj,
    const ushort* __restrict__ FWq, const float* __restrict__ Sarr,
    const float* __restrict__ Tbarr,
    const ushort* __restrict__ FWoT, const float* __restrict__ bo,
    ushort* __restrict__ attn_map, float* __restrict__ stA_raw)
{
  __shared__ __align__(16) char LM[51200];
  __shared__ float sSum[64], sSum2[64];
  __shared__ float sStat[16];

  const int t = threadIdx.x;
  const int bid = blockIdx.x;
  const int b = bid >> 8, wh = (bid >> 3) & 31, ww0 = bid & 7;
  const int w = t >> 6, l = t & 63, q = l >> 4, r16 = l & 15;

  uint* sInP = (uint*)LM;            // [96][68] dwords (26112 B)
  ushort* sXn = (ushort*)LM;         // [64][136]

  if (t < 64) { sSum[t] = 0.f; sSum2[t] = 0.f; }
  if (t < 16) sStat[t] = 0.f;

  // ---- phase 0: stage concat(x,h) -> sInP[chp][col], col = window*16 + token ----
  {
    const float* xb = x + (size_t)b * 64 * PIX;
    const float* hb = h + (size_t)b * 128 * PIX;
    #pragma unroll
    for (int it = 0; it < 6; it++) {
      int item = it * 256 + t;                 // [0,1536)
      int wv = item & 3, r = (item >> 2) & 3, chp = item >> 4;
      int ch0 = chp * 2;
      int gpix = (wh * 4 + r) * 128 + ww0 * 16 + wv * 4;
      float4 a, c2;
      if (ch0 < 64) {
        a  = *reinterpret_cast<const float4*>(xb + (size_t)ch0 * PIX + gpix);
        c2 = *reinterpret_cast<const float4*>(xb + (size_t)(ch0 + 1) * PIX + gpix);
      } else {
        a  = *reinterpret_cast<const float4*>(hb + (size_t)(ch0 - 64) * PIX + gpix);
        c2 = *reinterpret_cast<const float4*>(hb + (size_t)(ch0 - 63) * PIX + gpix);
      }
      uint4 pkd;
      pkd.x = pk2(a.x, c2.x); pkd.y = pk2(a.y, c2.y);
      pkd.z = pk2(a.z, c2.z); pkd.w = pk2(a.w, c2.w);
      *reinterpret_cast<uint4*>(sInP + chp * 68 + wv * 16 + r * 4) = pkd;
    }
  }
  __syncthreads();   // B1

  // ---- phase 1: proj MFMA. wave w owns mt in {w, w+4}; nt = window 0..3 ----
  f32x4 acc1[2][4];
  {
    #pragma unroll
    for (int mi = 0; mi < 2; mi++)
      #pragma unroll
      for (int nt = 0; nt < 4; nt++) acc1[mi][nt] = (f32x4){0.f, 0.f, 0.f, 0.f};
    for (int ks = 0; ks < 6; ks++) {
      Frag bf[4];
      #pragma unroll
      for (int nt = 0; nt < 4; nt++)
        #pragma unroll
        for (int s = 0; s < 4; s++)
          bf[nt].u[s] = sInP[(ks * 16 + q * 4 + s) * 68 + nt * 16 + r16];
      #pragma unroll
      for (int mi = 0; mi < 2; mi++) {
        Frag af;
        af.u4 = *reinterpret_cast<const uint4*>(FWp + (((w + mi * 4) * 6 + ks) * 64 + l) * 8);
        #pragma unroll
        for (int nt = 0; nt < 4; nt++)
          acc1[mi][nt] = __builtin_amdgcn_mfma_f32_16x16x32_bf16(af.s, bf[nt].s, acc1[mi][nt], 0, 0, 0);
      }
    }
  }
  __syncthreads();   // B2: all sInP reads done; sXn overlays

  // ---- phase 1b: bias, pack raw p -> sXn, per-token LN stats (fp32) ----
  {
    float pst[4] = {0.f, 0.f, 0.f, 0.f}, pst2[4] = {0.f, 0.f, 0.f, 0.f};
    #pragma unroll
    for (int mi = 0; mi < 2; mi++) {
      int o0 = (w + mi * 4) * 16 + q * 4;
      const float4 bv = *reinterpret_cast<const float4*>(bproj + o0);
      #pragma unroll
      for (int nt = 0; nt < 4; nt++) {
        float v0 = acc1[mi][nt][0] + bv.x, v1 = acc1[mi][nt][1] + bv.y;
        float v2 = acc1[mi][nt][2] + bv.z, v3 = acc1[mi][nt][3] + bv.w;
        uint2 pk; pk.x = pk2(v0, v1); pk.y = pk2(v2, v3);
        *reinterpret_cast<uint2*>(sXn + (nt * 16 + r16) * 136 + o0) = pk;
        pst[nt]  += v0 + v1 + v2 + v3;
        pst2[nt] += v0 * v0 + v1 * v1 + v2 * v2 + v3 * v3;
      }
    }
    #pragma unroll
    for (int nt = 0; nt < 4; nt++) {
      float s = pst[nt], s2 = pst2[nt];
      s  += __shfl_xor(s, 16);  s  += __shfl_xor(s, 32);
      s2 += __shfl_xor(s2, 16); s2 += __shfl_xor(s2, 32);
      if (q == 0) {
        atomicAdd(&sSum[nt * 16 + r16], s);
        atomicAdd(&sSum2[nt * 16 + r16], s2);
      }
    }
  }
  __syncthreads();   // B3: sXn + stats ready

  // ---- phase 2: hoist xn frags; QK GEMM -> slices; V GEMM held in regs ----
  float rstd_[4], mr_[4];
  f32x4 accV[2][4];
  {
    Frag bfh[4][4];   // [ks][nt] — all sXn reads happen here
    #pragma unroll
    for (int ks = 0; ks < 4; ks++)
      #pragma unroll
      for (int nt = 0; nt < 4; nt++)
        bfh[ks][nt].u4 = *reinterpret_cast<const uint4*>(sXn + (nt * 16 + r16) * 136 + ks * 32 + q * 8);

    #pragma unroll
    for (int nt = 0; nt < 4; nt++) {
      int tok = nt * 16 + r16;
      float mu = sSum[tok] * 0.0078125f;
      float var = sSum2[tok] * 0.0078125f - mu * mu;
      rstd_[nt] = rsqrtf(var + EPSF);
      mr_[nt] = -mu * rstd_[nt];
    }

    ushort* sQKu = (ushort*)(LM + 17408);
    #pragma unroll
    for (int mi = 0; mi < 4; mi++) {        // Q,K tiles: mt = w + mi*4 < 16
      int mt = w + mi * 4;
      f32x4 accq[4];
      #pragma unroll
      for (int nt = 0; nt < 4; nt++) accq[nt] = (f32x4){0.f, 0.f, 0.f, 0.f};
      #pragma unroll
      for (int ks = 0; ks < 4; ks++) {
        Frag af;
        af.u4 = *reinterpret_cast<const uint4*>(FWq + ((mt * 4 + ks) * 64 + l) * 8);
        #pragma unroll
        for (int nt = 0; nt < 4; nt++)
          accq[nt] = __builtin_amdgcn_mfma_f32_16x16x32_bf16(af.s, bfh[ks][nt].s, accq[nt], 0, 0, 0);
      }
      int oo = mt * 16 + q * 4;
      const float4 S4  = *reinterpret_cast<const float4*>(Sarr + oo);
      const float4 Tb4 = *reinterpret_cast<const float4*>(Tbarr + oo);
      #pragma unroll
      for (int nt = 0; nt < 4; nt++) {
        float v0 = fmaf(rstd_[nt], accq[nt][0], fmaf(mr_[nt], S4.x, Tb4.x));
        float v1 = fmaf(rstd_[nt], accq[nt][1], fmaf(mr_[nt], S4.y, Tb4.y));
        float v2 = fmaf(rstd_[nt], accq[nt][2], fmaf(mr_[nt], S4.z, Tb4.z));
        float v3 = fmaf(rstd_[nt], accq[nt][3], fmaf(mr_[nt], S4.w, Tb4.w));
        uint2 pk; pk.x = pk2(v0, v1); pk.y = pk2(v2, v3);
        *reinterpret_cast<uint2*>(sQKu + nt * 4224 + r16 * 264 + oo) = pk;
      }
    }
    #pragma unroll
    for (int mi = 0; mi < 2; mi++) {        // V tiles: mt = w+16, w+20
      int mt = w + 16 + mi * 4;
      #pragma unroll
      for (int nt = 0; nt < 4; nt++) accV[mi][nt] = (f32x4){0.f, 0.f, 0.f, 0.f};
      #pragma unroll
      for (int ks = 0; ks < 4; ks++) {
        Frag af;
        af.u4 = *reinterpret_cast<const uint4*>(FWq + ((mt * 4 + ks) * 64 + l) * 8);
        #pragma unroll
        for (int nt = 0; nt < 4; nt++)
          accV[mi][nt] = __builtin_amdgcn_mfma_f32_16x16x32_bf16(af.s, bfh[ks][nt].s, accV[mi][nt], 0, 0, 0);
      }
    }
  }
  __syncthreads();   // B4: all waves' sXn reads drained; R0 free for V

  // ---- phase 2b: V epilogue -> R0 [0,16384) ----
  {
    ushort* sVu = (ushort*)LM;
    #pragma unroll
    for (int mi = 0; mi < 2; mi++) {
      int mt = w + 16 + mi * 4;
      int oo = mt * 16 + q * 4;
      const float4 S4  = *reinterpret_cast<const float4*>(Sarr + oo);
      const float4 Tb4 = *reinterpret_cast<const float4*>(Tbarr + oo);
      #pragma unroll
      for (int nt = 0; nt < 4; nt++) {
        float v0 = fmaf(rstd_[nt], accV[mi][nt][0], fmaf(mr_[nt], S4.x, Tb4.x));
        float v1 = fmaf(rstd_[nt], accV[mi][nt][1], fmaf(mr_[nt], S4.y, Tb4.y));
        float v2 = fmaf(rstd_[nt], accV[mi][nt][2], fmaf(mr_[nt], S4.z, Tb4.z));
        float v3 = fmaf(rstd_[nt], accV[mi][nt][3], fmaf(mr_[nt], S4.w, Tb4.w));
        ushort* vd = sVu + nt * 2048 + (oo - 256) * 16 + r16;
        vd[0] = f2bf(v0); vd[16] = f2bf(v1); vd[32] = f2bf(v2); vd[48] = f2bf(v3);
      }
    }
  }
  __syncthreads();   // B4b: V visible to all waves

  // ---- phase 3: scores + softmax + PV, wave = window w ----
  {
    const float scale = 0.17677669529663687f;
    ushort* sQKw = (ushort*)(LM + 17408 + w * 8448);
    ushort* sPw  = sQKw;
    Frag af4[4], bf4[4];
    #pragma unroll
    for (int hd = 0; hd < 4; hd++) {
      af4[hd].u4 = *reinterpret_cast<const uint4*>(sQKw + r16 * 264 + hd * 32 + q * 8);
      bf4[hd].u4 = *reinterpret_cast<const uint4*>(sQKw + r16 * 264 + 128 + hd * 32 + q * 8);
    }
    #pragma unroll
    for (int hd = 0; hd < 4; hd++) {
      if (l < 32) {
        int row = l >> 1, hz = l & 1;
        uint4 z = {0u, 0u, 0u, 0u};
        *reinterpret_cast<uint4*>(sPw + hd * 512 + row * 32 + 16 + hz * 8) = z;
      }
    }
    f32x4 sc[4];
    #pragma unroll
    for (int hd = 0; hd < 4; hd++) {
      f32x4 z4 = (f32x4){0.f, 0.f, 0.f, 0.f};
      sc[hd] = __builtin_amdgcn_mfma_f32_16x16x32_bf16(af4[hd].s, bf4[hd].s, z4, 0, 0, 0);
    }
    #pragma unroll
    for (int hd = 0; hd < 4; hd++) {
      ushort* pd = sPw + hd * 512 + (q * 4) * 32 + r16;
      #pragma unroll
      for (int r = 0; r < 4; r++) {
        float sv = sc[hd][r] * scale;
        float mx = sv;
        mx = fmaxf(mx, __shfl_xor(mx, 1));
        mx = fmaxf(mx, __shfl_xor(mx, 2));
        mx = fmaxf(mx, __shfl_xor(mx, 4));
        mx = fmaxf(mx, __shfl_xor(mx, 8));
        float e = __expf(sv - mx);
        float sm = e;
        sm += __shfl_xor(sm, 1); sm += __shfl_xor(sm, 2);
        sm += __shfl_xor(sm, 4); sm += __shfl_xor(sm, 8);
        pd[r * 32] = f2bf(e * frcp(sm));
      }
    }
    // PV -> sO at slice[4096,8448); V from R0
    ushort* sOw = sQKw + 2048;               // +4096 B
    ushort* sVw = (ushort*)LM + w * 2048;    // window w's V (4096 B)
    #pragma unroll
    for (int hd = 0; hd < 4; hd++) {
      Frag pa;
      pa.u4 = *reinterpret_cast<const uint4*>(sPw + hd * 512 + r16 * 32 + q * 8);
      #pragma unroll
      for (int nt2 = 0; nt2 < 2; nt2++) {
        int ch = hd * 32 + nt2 * 16 + r16;
        int off = (q < 2) ? q * 8 : 0;
        Frag vf;
        vf.u4 = *reinterpret_cast<const uint4*>(sVw + ch * 16 + off);
        f32x4 z4 = (f32x4){0.f, 0.f, 0.f, 0.f};
        f32x4 o4 = __builtin_amdgcn_mfma_f32_16x16x32_bf16(pa.s, vf.s, z4, 0, 0, 0);
        ushort* od = sOw + (q * 4) * 136 + ch;
        od[0] = f2bf(o4[0]); od[136] = f2bf(o4[1]);
        od[272] = f2bf(o4[2]); od[408] = f2bf(o4[3]);
      }
    }
  }
  __syncthreads();   // B5: all sO ready; R0 (V) dead -> sFin

  // ---- phase 4: Wo MFMA. wave w owns ntg in {w, w+4}; nt = window ----
  {
    ushort* sFinu = (ushort*)LM;
    Frag a4[4][4];
    #pragma unroll
    for (int nt = 0; nt < 4; nt++) {
      ushort* sOnt = (ushort*)(LM + 17408 + nt * 8448 + 4096);
      #pragma unroll
      for (int ks = 0; ks < 4; ks++)
        a4[nt][ks].u4 = *reinterpret_cast<const uint4*>(sOnt + r16 * 136 + ks * 32 + q * 8);
    }
    #pragma unroll
    for (int mi2 = 0; mi2 < 2; mi2++) {
      int ntg = w + mi2 * 4;
      f32x4 acw[4];
      #pragma unroll
      for (int nt = 0; nt < 4; nt++) acw[nt] = (f32x4){0.f, 0.f, 0.f, 0.f};
      #pragma unroll
      for (int ks = 0; ks < 4; ks++) {
        Frag bfw;
        bfw.u4 = *reinterpret_cast<const uint4*>(FWoT + ((ntg * 4 + ks) * 64 + l) * 8);
        #pragma unroll
        for (int nt = 0; nt < 4; nt++)
          acw[nt] = __builtin_amdgcn_mfma_f32_16x16x32_bf16(a4[nt][ks].s, bfw.s, acw[nt], 0, 0, 0);
      }
      int ch = ntg * 16 + r16;
      float bb = bo[ch];
      #pragma unroll
      for (int nt = 0; nt < 4; nt++) {
        uint2 pk;
        pk.x = pk2(acw[nt][0] + bb, acw[nt][1] + bb);
        pk.y = pk2(acw[nt][2] + bb, acw[nt][3] + bb);
        *reinterpret_cast<uint2*>(sFinu + nt * 2048 + ch * 16 + q * 4) = pk;
      }
    }
  }
  __syncthreads();   // B6

  // ---- phase 5: coalesced writeout (2 windows per 16B) + GN partial stats ----
  {
    ushort* sFinu = (ushort*)LM;
    #pragma unroll
    for (int it = 0; it < 4; it++) {
      int seg = it * 256 + t;            // [0,1024)
      int ch = seg >> 3, r = (seg >> 1) & 3, half = seg & 1;
      const ushort* f0 = sFinu + (half * 2    ) * 2048;
      const ushort* f1 = sFinu + (half * 2 + 1) * 2048;
      uint2 a  = *reinterpret_cast<const uint2*>(f0 + ch * 16 + r * 4);
      uint2 c2 = *reinterpret_cast<const uint2*>(f1 + ch * 16 + r * 4);
      uint4 val = {a.x, a.y, c2.x, c2.y};
      *reinterpret_cast<uint4*>(attn_map + (size_t)(b * 128 + ch) * PIX
                                + (wh * 4 + r) * 128 + ww0 * 16 + half * 8) = val;
      float sv = 0.f, sv2 = 0.f;
      uint uu[4] = {val.x, val.y, val.z, val.w};
      #pragma unroll
      for (int k2 = 0; k2 < 4; k2++) {
        float fv0 = bf2f((ushort)(uu[k2] & 0xFFFFu));
        float fv1 = bf2f((ushort)(uu[k2] >> 16));
        sv += fv0 + fv1; sv2 += fv0 * fv0 + fv1 * fv1;
      }
      sv  += __shfl_xor(sv, 1);  sv  += __shfl_xor(sv, 2);  sv  += __shfl_xor(sv, 4);
      sv2 += __shfl_xor(sv2, 1); sv2 += __shfl_xor(sv2, 2); sv2 += __shfl_xor(sv2, 4);
      if ((t & 7) == 0) {
        int g = ch >> 4;
        atomicAdd(&sStat[g * 2], sv);
        atomicAdd(&sStat[g * 2 + 1], sv2);
      }
    }
  }
  __syncthreads();
  if (t < 16) atomicAdd(&stA_raw[b * 16 + t], sStat[t]);
}

// ---------------- GN + gates MFMA + LSTM update (+stats for GN2) ----------------
// (round-10 v3; frcp transcendentals; NO setprio)
__global__ __launch_bounds__(256, 4) void k_gates(
    const ushort* __restrict__ attn_map, const float* __restrict__ stA_raw,
    const float* __restrict__ gn_g, const float* __restrict__ gn_b,
    const ushort* __restrict__ FWg, const float* __restrict__ bgates,
    const float* __restrict__ c, float* __restrict__ cnext,
    ushort* __restrict__ tbuf, float* __restrict__ stB_raw)
{
  __shared__ uint sG2[32 * 66];     // [px][ch-pair dwords + 2 pad] = 8448 B
  __shared__ float sA[128], sB[128];
  __shared__ float sStat[16];
  const int t = threadIdx.x, bid = blockIdx.x;
  const int b = bid >> 9, p0 = (bid & 511) * 32;
  const int w = t >> 6, l = t & 63, q = l >> 4, r16 = l & 15;

  if (t < 128) {
    int g = t >> 4;
    const float invN = 1.f / 262144.f;
    float mu = stA_raw[b * 16 + g * 2] * invN;
    float var = stA_raw[b * 16 + g * 2 + 1] * invN - mu * mu;
    float rs = rsqrtf(var + EPSF);
    float A = rs * gn_g[t];
    sA[t] = A; sB[t] = gn_b[t] - mu * A;
  }
  if (t >= 240) sStat[t - 240] = 0.f;
  __syncthreads();

  // ---- staging: GN(attn) -> sG2[px][ch] (transposed) ----
  {
    int pr = t >> 2, px0 = (t & 3) * 8;
    int c0 = pr * 2;
    const ushort* ab = attn_map + (size_t)(b * 128 + c0) * PIX + p0 + px0;
    uint4 a0 = *reinterpret_cast<const uint4*>(ab);
    uint4 a1 = *reinterpret_cast<const uint4*>(ab + PIX);
    float A0 = sA[c0], B0 = sB[c0], A1 = sA[c0 + 1], B1 = sB[c0 + 1];
    uint u0[4] = {a0.x, a0.y, a0.z, a0.w};
    uint u1[4] = {a1.x, a1.y, a1.z, a1.w};
    #pragma unroll
    for (int j = 0; j < 4; j++) {
      float v0lo = bf2f((ushort)(u0[j] & 0xFFFFu)) * A0 + B0;
      float v0hi = bf2f((ushort)(u0[j] >> 16)) * A0 + B0;
      float v1lo = bf2f((ushort)(u1[j] & 0xFFFFu)) * A1 + B1;
      float v1hi = bf2f((ushort)(u1[j] >> 16)) * A1 + B1;
      sG2[(px0 + 2 * j) * 66 + pr]     = pk2(v0lo, v1lo);
      sG2[(px0 + 2 * j + 1) * 66 + pr] = pk2(v0hi, v1hi);
    }
  }

  // ---- prefetch c ----
  float4 cv[2][2];
  #pragma unroll
  for (int j = 0; j < 2; j++) {
    int ch = (w + 4 * j) * 16 + r16;
    const float* cb = c + (size_t)(b * 128 + ch) * PIX + p0 + q * 4;
    cv[j][0] = *reinterpret_cast<const float4*>(cb);
    cv[j][1] = *reinterpret_cast<const float4*>(cb + 16);
  }
  __syncthreads();

  // ---- gates GEMM: D[px][ch]; acc[gate][j][pxt], ch tile = w + 4j + 8*gate ----
  f32x4 acc[4][2][2];
  #pragma unroll
  for (int g2 = 0; g2 < 4; g2++)
    #pragma unroll
    for (int j = 0; j < 2; j++)
      #pragma unroll
      for (int pxt = 0; pxt < 2; pxt++) acc[g2][j][pxt] = (f32x4){0.f, 0.f, 0.f, 0.f};

  const ushort* sGu = (const ushort*)sG2;
  for (int ks = 0; ks < 4; ks++) {
    Frag af[2];
    #pragma unroll
    for (int pxt = 0; pxt < 2; pxt++)
      af[pxt].u4 = *reinterpret_cast<const uint4*>(sGu + (pxt * 16 + r16) * 132 + ks * 32 + q * 8);
    #pragma unroll
    for (int g2 = 0; g2 < 4; g2++) {
      #pragma unroll
      for (int j = 0; j < 2; j++) {
        int ct = w + 4 * j + 8 * g2;
        Frag bfw;
        bfw.u4 = *reinterpret_cast<const uint4*>(FWg + ((ct * 4 + ks) * 64 + l) * 8);
        #pragma unroll
        for (int pxt = 0; pxt < 2; pxt++)
          acc[g2][j][pxt] = __builtin_amdgcn_mfma_f32_16x16x32_bf16(af[pxt].s, bfw.s, acc[g2][j][pxt], 0, 0, 0);
      }
    }
  }

  // ---- LSTM epilogue: vectorized c/cnext/tbuf ----
  float gs[2] = {0.f, 0.f}, gs2[2] = {0.f, 0.f};
  #pragma unroll
  for (int j = 0; j < 2; j++) {
    int ch = (w + 4 * j) * 16 + r16;
    float bi = bgates[ch], bff = bgates[128 + ch], bog = bgates[256 + ch], bgg = bgates[384 + ch];
    #pragma unroll
    for (int pxt = 0; pxt < 2; pxt++) {
      size_t gbase = (size_t)(b * 128 + ch) * PIX + p0 + pxt * 16 + q * 4;
      const float cc[4] = {cv[j][pxt].x, cv[j][pxt].y, cv[j][pxt].z, cv[j][pxt].w};
      float cn[4], tv[4];
      #pragma unroll
      for (int r = 0; r < 4; r++) {
        float ig = fsigmoid(acc[0][j][pxt][r] + bi);
        float fg = fsigmoid(acc[1][j][pxt][r] + bff);
        float og = fsigmoid(acc[2][j][pxt][r] + bog);
        float gg = ftanh   (acc[3][j][pxt][r] + bgg);
        cn[r] = fg * cc[r] + ig * gg;
        tv[r] = og * ftanh(cn[r]);
        gs[j] += tv[r]; gs2[j] += tv[r] * tv[r];
      }
      float4 cno = {cn[0], cn[1], cn[2], cn[3]};
      *reinterpret_cast<float4*>(cnext + gbase) = cno;
      uint2 tpk;
      tpk.x = pk2(tv[0], tv[1]); tpk.y = pk2(tv[2], tv[3]);
      *reinterpret_cast<uint2*>(tbuf + gbase) = tpk;
    }
  }
  #pragma unroll
  for (int j = 0; j < 2; j++) {
    float s = gs[j], s2 = gs2[j];
    s += __shfl_xor(s, 1); s += __shfl_xor(s, 2); s += __shfl_xor(s, 4);
    s += __shfl_xor(s, 8); s += __shfl_xor(s, 16); s += __shfl_xor(s, 32);
    s2 += __shfl_xor(s2, 1); s2 += __shfl_xor(s2, 2); s2 += __shfl_xor(s2, 4);
    s2 += __shfl_xor(s2, 8); s2 += __shfl_xor(s2, 16); s2 += __shfl_xor(s2, 32);
    if (l == 0) {
      int g = w + 4 * j;
      atomicAdd(&sStat[g * 2], s);
      atomicAdd(&sStat[g * 2 + 1], s2);
    }
  }
  __syncthreads();
  if (t < 16) atomicAdd(&stB_raw[b * 16 + t], sStat[t]);
}

// ---------------- hnext = GN2(tbuf), inline stats finalize ----------------
__global__ __launch_bounds__(256) void k_gnout(
    const ushort* __restrict__ tbuf, const float* __restrict__ stB_raw,
    const float* __restrict__ gn_g, const float* __restrict__ gn_b,
    float* __restrict__ hnext)
{
  size_t idx = ((size_t)blockIdx.x * 256 + threadIdx.x) * 8;
  if (idx >= (size_t)16777216) return;
  int chrow = (int)(idx >> 14);
  int b = chrow >> 7, ch = chrow & 127, g = ch >> 4;
  const float invN = 1.f / 262144.f;
  float mu = stB_raw[b * 16 + g * 2] * invN;
  float var = stB_raw[b * 16 + g * 2 + 1] * invN - mu * mu;
  float rstd = rsqrtf(var + EPSF);
  float A = gn_g[ch] * rstd, Bv = gn_b[ch] - mu * A;
  uint4 u = *reinterpret_cast<const uint4*>(tbuf + idx);
  float4 o0, o1;
  o0.x = bf2f((ushort)(u.x & 0xFFFFu)) * A + Bv;
  o0.y = bf2f((ushort)(u.x >> 16)) * A + Bv;
  o0.z = bf2f((ushort)(u.y & 0xFFFFu)) * A + Bv;
  o0.w = bf2f((ushort)(u.y >> 16)) * A + Bv;
  o1.x = bf2f((ushort)(u.z & 0xFFFFu)) * A + Bv;
  o1.y = bf2f((ushort)(u.z >> 16)) * A + Bv;
  o1.z = bf2f((ushort)(u.w & 0xFFFFu)) * A + Bv;
  o1.w = bf2f((ushort)(u.w >> 16)) * A + Bv;
  *reinterpret_cast<float4*>(hnext + idx) = o0;
  *reinterpret_cast<float4*>(hnext + idx + 4) = o1;
}

extern "C" void kernel_launch(void* const* d_in, const int* in_sizes, int n_in,
                              void* d_out, int out_size, void* d_ws, size_t ws_size,
                              hipStream_t stream) {
  (void)in_sizes; (void)n_in; (void)out_size; (void)ws_size;
  const float* x      = (const float*)d_in[0];
  const float* h      = (const float*)d_in[1];
  const float* c      = (const float*)d_in[2];
  const float* Wproj  = (const float*)d_in[3];
  const float* bproj  = (const float*)d_in[4];
  const float* ln_g   = (const float*)d_in[5];
  const float* ln_b   = (const float*)d_in[6];
  const float* Wqkv   = (const float*)d_in[7];
  const float* bqkv   = (const float*)d_in[8];
  const float* Wo     = (const float*)d_in[9];
  const float* bo     = (const float*)d_in[10];
  const float* Wgates = (const float*)d_in[11];
  const float* bgates = (const float*)d_in[12];
  const float* gn_g   = (const float*)d_in[13];
  const float* gn_b   = (const float*)d_in[14];

  float* out = (float*)d_out;
  float* hnext = out;
  float* cnext = out + 16777216;

  char* W = (char*)d_ws;
  ushort* attn = (ushort*)W;                          // 32 MB bf16
  ushort* tbuf = (ushort*)(W + 33554432);             // 32 MB bf16
  size_t off = 67108864;
  ushort* FWp = (ushort*)(W + off); off += 49152;
  ushort* FWq = (ushort*)(W + off); off += 98304;
  ushort* FWo = (ushort*)(W + off); off += 32768;
  ushort* FWg = (ushort*)(W + off); off += 131072;
  float* stA_raw = (float*)(W + off); off += 512;
  float* stB_raw = (float*)(W + off); off += 512;
  float* Sarr    = (float*)(W + off); off += 1536;
  float* Tbarr   = (float*)(W + off); off += 1536;

  hipMemsetAsync(stA_raw, 0, 1024, stream);

  k_prep<<<78, 256, 0, stream>>>(Wproj, Wqkv, Wo, Wgates, ln_g, ln_b, bqkv,
                                 FWp, FWq, FWo, FWg, Sarr, Tbarr);

  k_attn<<<2048, 256, 0, stream>>>(x, h, FWp, bproj, FWq, Sarr, Tbarr,
                                   FWo, bo, attn, stA_raw);
  k_gates<<<4096, 256, 0, stream>>>(attn, stA_raw, gn_g, gn_b, FWg, bgates,
                                    c, cnext, tbuf, stB_raw);
  k_gnout<<<8192, 256, 0, stream>>>(tbuf, stB_raw, gn_g, gn_b, hnext);
}

// Round 19
// 187.757 us; speedup vs baseline: 1.1503x; 1.0457x over previous
//
#include <hip/hip_runtime.h>
#include <math.h>

typedef unsigned int uint;
typedef unsigned short ushort;
typedef short s16x8 __attribute__((ext_vector_type(8)));
typedef float f32x4 __attribute__((ext_vector_type(4)));

#define PIX 16384
#define EPSF 1e-5f

__device__ __forceinline__ ushort f2bf(float f) {
  union { float f; uint u; } v; v.f = f;
  uint u = v.u;
  uint r = (u + 0x7FFFu + ((u >> 16) & 1u)) >> 16;
  return (ushort)r;
}
__device__ __forceinline__ float bf2f(ushort h) {
  union { uint u; float f; } v; v.u = ((uint)h) << 16;
  return v.f;
}
__device__ __forceinline__ uint pk2(float a, float b) {
  return (uint)f2bf(a) | ((uint)f2bf(b) << 16);
}
__device__ __forceinline__ float frcp(float x) { return __builtin_amdgcn_rcpf(x); }
__device__ __forceinline__ float fsigmoid(float v) { return frcp(1.f + __expf(-v)); }
__device__ __forceinline__ float ftanh(float v) { return 1.f - 2.f * frcp(__expf(2.f * v) + 1.f); }

union Frag { uint4 u4; uint u[4]; s16x8 s; };

// ---------------- merged weight fragment prep (+ folded-LN S/Tb vectors) ----------------
// frag (mt, ks): lane l elem j = W[mt*16 + (l&15)][ks*32 + (l>>4)*8 + j]
// FWq columns pre-scaled by ln_g. Tail threads (idx>=19456) compute Sarr/Tbarr.
__global__ void k_prep(const float* __restrict__ Wp, const float* __restrict__ Wq,
                       const float* __restrict__ Wo, const float* __restrict__ Wg,
                       const float* __restrict__ ln_g, const float* __restrict__ ln_b,
                       const float* __restrict__ bqkv,
                       ushort* __restrict__ FWp, ushort* __restrict__ FWq,
                       ushort* __restrict__ FWo, ushort* __restrict__ FWg,
                       float* __restrict__ Sarr, float* __restrict__ Tbarr) {
  int idx = blockIdx.x * 256 + threadIdx.x;   // [0, 19968)
  if (idx >= 19456) {
    int o = idx - 19456;
    if (o >= 384) return;
    float S = 0.f, T = 0.f;
    const float* wr = Wq + (size_t)o * 128;
    for (int i = 0; i < 128; i++) {
      float wv = wr[i];
      S = fmaf(wv, ln_g[i], S);
      T = fmaf(wv, ln_b[i], T);
    }
    Sarr[o] = S;
    Tbarr[o] = T + bqkv[o];
    return;
  }
  const float* W; ushort* F; int KS, ldw, rel; bool scale = false;
  if (idx < 3072)       { W = Wp; F = FWp; KS = 6; ldw = 192; rel = idx; }
  else if (idx < 9216)  { W = Wq; F = FWq; KS = 4; ldw = 128; rel = idx - 3072; scale = true; }
  else if (idx < 11264) { W = Wo; F = FWo; KS = 4; ldw = 128; rel = idx - 9216; }
  else                  { W = Wg; F = FWg; KS = 4; ldw = 128; rel = idx - 11264; }
  int l = rel & 63, rest = rel >> 6;
  int ks = rest % KS, mt = rest / KS;
  int col = ks * 32 + (l >> 4) * 8;
  const float* src = W + (size_t)(mt * 16 + (l & 15)) * ldw + col;
  float g[8] = {1.f, 1.f, 1.f, 1.f, 1.f, 1.f, 1.f, 1.f};
  if (scale) {
    #pragma unroll
    for (int j = 0; j < 8; j++) g[j] = ln_g[col + j];
  }
  uint4 v;
  v.x = pk2(src[0] * g[0], src[1] * g[1]);
  v.y = pk2(src[2] * g[2], src[3] * g[3]);
  v.z = pk2(src[4] * g[4], src[5] * g[5]);
  v.w = pk2(src[6] * g[6], src[7] * g[7]);
  *reinterpret_cast<uint4*>(F + (size_t)rel * 8) = v;
}

// ---------------- fused proj + (folded LN) + window MHSA + Wo (+GN stats) ----------------
// (round-18 structure; phase-1 FWp fragments hoisted above B1 to hide L2 latency)
__global__ __launch_bounds__(256, 3) void k_attn(
    const float* __restrict__ x, const float* __restrict__ h,
    const ushort* __restrict__ FWp, const float* __restrict__ bproj,
    const ushort* __restrict__ FWq, const float* __restrict__ Sarr,
    const float* __restrict__ Tbarr,
    const ushort* __restrict__ FWoT, const float* __restrict__ bo,
    ushort* __restrict__ attn_map, float* __restrict__ stA_raw)
{
  __shared__ __align__(16) char LM[51200];
  __shared__ float sSum[64], sSum2[64];
  __shared__ float sStat[16];

  const int t = threadIdx.x;
  const int bid = blockIdx.x;
  const int b = bid >> 8, wh = (bid >> 3) & 31, ww0 = bid & 7;
  const int w = t >> 6, l = t & 63, q = l >> 4, r16 = l & 15;

  uint* sInP = (uint*)LM;            // [96][68] dwords (26112 B)
  ushort* sXn = (ushort*)LM;         // [64][136]

  if (t < 64) { sSum[t] = 0.f; sSum2[t] = 0.f; }
  if (t < 16) sStat[t] = 0.f;

  // ---- hoisted phase-1 weight fragments: issue before staging barrier ----
  Frag wpf[2][6];
  #pragma unroll
  for (int mi = 0; mi < 2; mi++)
    #pragma unroll
    for (int ks = 0; ks < 6; ks++)
      wpf[mi][ks].u4 = *reinterpret_cast<const uint4*>(FWp + (((w + mi * 4) * 6 + ks) * 64 + l) * 8);

  // ---- phase 0: stage concat(x,h) -> sInP[chp][col], col = window*16 + token ----
  {
    const float* xb = x + (size_t)b * 64 * PIX;
    const float* hb = h + (size_t)b * 128 * PIX;
    #pragma unroll
    for (int it = 0; it < 6; it++) {
      int item = it * 256 + t;                 // [0,1536)
      int wv = item & 3, r = (item >> 2) & 3, chp = item >> 4;
      int ch0 = chp * 2;
      int gpix = (wh * 4 + r) * 128 + ww0 * 16 + wv * 4;
      float4 a, c2;
      if (ch0 < 64) {
        a  = *reinterpret_cast<const float4*>(xb + (size_t)ch0 * PIX + gpix);
        c2 = *reinterpret_cast<const float4*>(xb + (size_t)(ch0 + 1) * PIX + gpix);
      } else {
        a  = *reinterpret_cast<const float4*>(hb + (size_t)(ch0 - 64) * PIX + gpix);
        c2 = *reinterpret_cast<const float4*>(hb + (size_t)(ch0 - 63) * PIX + gpix);
      }
      uint4 pkd;
      pkd.x = pk2(a.x, c2.x); pkd.y = pk2(a.y, c2.y);
      pkd.z = pk2(a.z, c2.z); pkd.w = pk2(a.w, c2.w);
      *reinterpret_cast<uint4*>(sInP + chp * 68 + wv * 16 + r * 4) = pkd;
    }
  }
  __syncthreads();   // B1

  // ---- phase 1: proj MFMA. wave w owns mt in {w, w+4}; nt = window 0..3 ----
  f32x4 acc1[2][4];
  {
    #pragma unroll
    for (int mi = 0; mi < 2; mi++)
      #pragma unroll
      for (int nt = 0; nt < 4; nt++) acc1[mi][nt] = (f32x4){0.f, 0.f, 0.f, 0.f};
    for (int ks = 0; ks < 6; ks++) {
      Frag bf[4];
      #pragma unroll
      for (int nt = 0; nt < 4; nt++)
        #pragma unroll
        for (int s = 0; s < 4; s++)
          bf[nt].u[s] = sInP[(ks * 16 + q * 4 + s) * 68 + nt * 16 + r16];
      #pragma unroll
      for (int mi = 0; mi < 2; mi++) {
        #pragma unroll
        for (int nt = 0; nt < 4; nt++)
          acc1[mi][nt] = __builtin_amdgcn_mfma_f32_16x16x32_bf16(wpf[mi][ks].s, bf[nt].s, acc1[mi][nt], 0, 0, 0);
      }
    }
  }
  __syncthreads();   // B2: all sInP reads done; sXn overlays

  // ---- phase 1b: bias, pack raw p -> sXn, per-token LN stats (fp32) ----
  {
    float pst[4] = {0.f, 0.f, 0.f, 0.f}, pst2[4] = {0.f, 0.f, 0.f, 0.f};
    #pragma unroll
    for (int mi = 0; mi < 2; mi++) {
      int o0 = (w + mi * 4) * 16 + q * 4;
      const float4 bv = *reinterpret_cast<const float4*>(bproj + o0);
      #pragma unroll
      for (int nt = 0; nt < 4; nt++) {
        float v0 = acc1[mi][nt][0] + bv.x, v1 = acc1[mi][nt][1] + bv.y;
        float v2 = acc1[mi][nt][2] + bv.z, v3 = acc1[mi][nt][3] + bv.w;
        uint2 pk; pk.x = pk2(v0, v1); pk.y = pk2(v2, v3);
        *reinterpret_cast<uint2*>(sXn + (nt * 16 + r16) * 136 + o0) = pk;
        pst[nt]  += v0 + v1 + v2 + v3;
        pst2[nt] += v0 * v0 + v1 * v1 + v2 * v2 + v3 * v3;
      }
    }
    #pragma unroll
    for (int nt = 0; nt < 4; nt++) {
      float s = pst[nt], s2 = pst2[nt];
      s  += __shfl_xor(s, 16);  s  += __shfl_xor(s, 32);
      s2 += __shfl_xor(s2, 16); s2 += __shfl_xor(s2, 32);
      if (q == 0) {
        atomicAdd(&sSum[nt * 16 + r16], s);
        atomicAdd(&sSum2[nt * 16 + r16], s2);
      }
    }
  }
  __syncthreads();   // B3: sXn + stats ready

  // ---- phase 2: hoist xn frags; QK GEMM -> slices; V GEMM held in regs ----
  float rstd_[4], mr_[4];
  f32x4 accV[2][4];
  {
    Frag bfh[4][4];   // [ks][nt] — all sXn reads happen here
    #pragma unroll
    for (int ks = 0; ks < 4; ks++)
      #pragma unroll
      for (int nt = 0; nt < 4; nt++)
        bfh[ks][nt].u4 = *reinterpret_cast<const uint4*>(sXn + (nt * 16 + r16) * 136 + ks * 32 + q * 8);

    #pragma unroll
    for (int nt = 0; nt < 4; nt++) {
      int tok = nt * 16 + r16;
      float mu = sSum[tok] * 0.0078125f;
      float var = sSum2[tok] * 0.0078125f - mu * mu;
      rstd_[nt] = rsqrtf(var + EPSF);
      mr_[nt] = -mu * rstd_[nt];
    }

    ushort* sQKu = (ushort*)(LM + 17408);
    #pragma unroll
    for (int mi = 0; mi < 4; mi++) {        // Q,K tiles: mt = w + mi*4 < 16
      int mt = w + mi * 4;
      f32x4 accq[4];
      #pragma unroll
      for (int nt = 0; nt < 4; nt++) accq[nt] = (f32x4){0.f, 0.f, 0.f, 0.f};
      #pragma unroll
      for (int ks = 0; ks < 4; ks++) {
        Frag af;
        af.u4 = *reinterpret_cast<const uint4*>(FWq + ((mt * 4 + ks) * 64 + l) * 8);
        #pragma unroll
        for (int nt = 0; nt < 4; nt++)
          accq[nt] = __builtin_amdgcn_mfma_f32_16x16x32_bf16(af.s, bfh[ks][nt].s, accq[nt], 0, 0, 0);
      }
      int oo = mt * 16 + q * 4;
      const float4 S4  = *reinterpret_cast<const float4*>(Sarr + oo);
      const float4 Tb4 = *reinterpret_cast<const float4*>(Tbarr + oo);
      #pragma unroll
      for (int nt = 0; nt < 4; nt++) {
        float v0 = fmaf(rstd_[nt], accq[nt][0], fmaf(mr_[nt], S4.x, Tb4.x));
        float v1 = fmaf(rstd_[nt], accq[nt][1], fmaf(mr_[nt], S4.y, Tb4.y));
        float v2 = fmaf(rstd_[nt], accq[nt][2], fmaf(mr_[nt], S4.z, Tb4.z));
        float v3 = fmaf(rstd_[nt], accq[nt][3], fmaf(mr_[nt], S4.w, Tb4.w));
        uint2 pk; pk.x = pk2(v0, v1); pk.y = pk2(v2, v3);
        *reinterpret_cast<uint2*>(sQKu + nt * 4224 + r16 * 264 + oo) = pk;
      }
    }
    #pragma unroll
    for (int mi = 0; mi < 2; mi++) {        // V tiles: mt = w+16, w+20
      int mt = w + 16 + mi * 4;
      #pragma unroll
      for (int nt = 0; nt < 4; nt++) accV[mi][nt] = (f32x4){0.f, 0.f, 0.f, 0.f};
      #pragma unroll
      for (int ks = 0; ks < 4; ks++) {
        Frag af;
        af.u4 = *reinterpret_cast<const uint4*>(FWq + ((mt * 4 + ks) * 64 + l) * 8);
        #pragma unroll
        for (int nt = 0; nt < 4; nt++)
          accV[mi][nt] = __builtin_amdgcn_mfma_f32_16x16x32_bf16(af.s, bfh[ks][nt].s, accV[mi][nt], 0, 0, 0);
      }
    }
  }
  __syncthreads();   // B4: all waves' sXn reads drained; R0 free for V

  // ---- phase 2b: V epilogue -> R0 [0,16384) ----
  {
    ushort* sVu = (ushort*)LM;
    #pragma unroll
    for (int mi = 0; mi < 2; mi++) {
      int mt = w + 16 + mi * 4;
      int oo = mt * 16 + q * 4;
      const float4 S4  = *reinterpret_cast<const float4*>(Sarr + oo);
      const float4 Tb4 = *reinterpret_cast<const float4*>(Tbarr + oo);
      #pragma unroll
      for (int nt = 0; nt < 4; nt++) {
        float v0 = fmaf(rstd_[nt], accV[mi][nt][0], fmaf(mr_[nt], S4.x, Tb4.x));
        float v1 = fmaf(rstd_[nt], accV[mi][nt][1], fmaf(mr_[nt], S4.y, Tb4.y));
        float v2 = fmaf(rstd_[nt], accV[mi][nt][2], fmaf(mr_[nt], S4.z, Tb4.z));
        float v3 = fmaf(rstd_[nt], accV[mi][nt][3], fmaf(mr_[nt], S4.w, Tb4.w));
        ushort* vd = sVu + nt * 2048 + (oo - 256) * 16 + r16;
        vd[0] = f2bf(v0); vd[16] = f2bf(v1); vd[32] = f2bf(v2); vd[48] = f2bf(v3);
      }
    }
  }
  __syncthreads();   // B4b: V visible to all waves

  // ---- phase 3: scores + softmax + PV, wave = window w ----
  {
    const float scale = 0.17677669529663687f;
    ushort* sQKw = (ushort*)(LM + 17408 + w * 8448);
    ushort* sPw  = sQKw;
    Frag af4[4], bf4[4];
    #pragma unroll
    for (int hd = 0; hd < 4; hd++) {
      af4[hd].u4 = *reinterpret_cast<const uint4*>(sQKw + r16 * 264 + hd * 32 + q * 8);
      bf4[hd].u4 = *reinterpret_cast<const uint4*>(sQKw + r16 * 264 + 128 + hd * 32 + q * 8);
    }
    #pragma unroll
    for (int hd = 0; hd < 4; hd++) {
      if (l < 32) {
        int row = l >> 1, hz = l & 1;
        uint4 z = {0u, 0u, 0u, 0u};
        *reinterpret_cast<uint4*>(sPw + hd * 512 + row * 32 + 16 + hz * 8) = z;
      }
    }
    f32x4 sc[4];
    #pragma unroll
    for (int hd = 0; hd < 4; hd++) {
      f32x4 z4 = (f32x4){0.f, 0.f, 0.f, 0.f};
      sc[hd] = __builtin_amdgcn_mfma_f32_16x16x32_bf16(af4[hd].s, bf4[hd].s, z4, 0, 0, 0);
    }
    #pragma unroll
    for (int hd = 0; hd < 4; hd++) {
      ushort* pd = sPw + hd * 512 + (q * 4) * 32 + r16;
      #pragma unroll
      for (int r = 0; r < 4; r++) {
        float sv = sc[hd][r] * scale;
        float mx = sv;
        mx = fmaxf(mx, __shfl_xor(mx, 1));
        mx = fmaxf(mx, __shfl_xor(mx, 2));
        mx = fmaxf(mx, __shfl_xor(mx, 4));
        mx = fmaxf(mx, __shfl_xor(mx, 8));
        float e = __expf(sv - mx);
        float sm = e;
        sm += __shfl_xor(sm, 1); sm += __shfl_xor(sm, 2);
        sm += __shfl_xor(sm, 4); sm += __shfl_xor(sm, 8);
        pd[r * 32] = f2bf(e * frcp(sm));
      }
    }
    // PV -> sO at slice[4096,8448); V from R0
    ushort* sOw = sQKw + 2048;               // +4096 B
    ushort* sVw = (ushort*)LM + w * 2048;    // window w's V (4096 B)
    #pragma unroll
    for (int hd = 0; hd < 4; hd++) {
      Frag pa;
      pa.u4 = *reinterpret_cast<const uint4*>(sPw + hd * 512 + r16 * 32 + q * 8);
      #pragma unroll
      for (int nt2 = 0; nt2 < 2; nt2++) {
        int ch = hd * 32 + nt2 * 16 + r16;
        int off = (q < 2) ? q * 8 : 0;
        Frag vf;
        vf.u4 = *reinterpret_cast<const uint4*>(sVw + ch * 16 + off);
        f32x4 z4 = (f32x4){0.f, 0.f, 0.f, 0.f};
        f32x4 o4 = __builtin_amdgcn_mfma_f32_16x16x32_bf16(pa.s, vf.s, z4, 0, 0, 0);
        ushort* od = sOw + (q * 4) * 136 + ch;
        od[0] = f2bf(o4[0]); od[136] = f2bf(o4[1]);
        od[272] = f2bf(o4[2]); od[408] = f2bf(o4[3]);
      }
    }
  }
  __syncthreads();   // B5: all sO ready; R0 (V) dead -> sFin

  // ---- phase 4: Wo MFMA. wave w owns ntg in {w, w+4}; nt = window ----
  {
    ushort* sFinu = (ushort*)LM;
    Frag a4[4][4];
    #pragma unroll
    for (int nt = 0; nt < 4; nt++) {
      ushort* sOnt = (ushort*)(LM + 17408 + nt * 8448 + 4096);
      #pragma unroll
      for (int ks = 0; ks < 4; ks++)
        a4[nt][ks].u4 = *reinterpret_cast<const uint4*>(sOnt + r16 * 136 + ks * 32 + q * 8);
    }
    #pragma unroll
    for (int mi2 = 0; mi2 < 2; mi2++) {
      int ntg = w + mi2 * 4;
      f32x4 acw[4];
      #pragma unroll
      for (int nt = 0; nt < 4; nt++) acw[nt] = (f32x4){0.f, 0.f, 0.f, 0.f};
      #pragma unroll
      for (int ks = 0; ks < 4; ks++) {
        Frag bfw;
        bfw.u4 = *reinterpret_cast<const uint4*>(FWoT + ((ntg * 4 + ks) * 64 + l) * 8);
        #pragma unroll
        for (int nt = 0; nt < 4; nt++)
          acw[nt] = __builtin_amdgcn_mfma_f32_16x16x32_bf16(a4[nt][ks].s, bfw.s, acw[nt], 0, 0, 0);
      }
      int ch = ntg * 16 + r16;
      float bb = bo[ch];
      #pragma unroll
      for (int nt = 0; nt < 4; nt++) {
        uint2 pk;
        pk.x = pk2(acw[nt][0] + bb, acw[nt][1] + bb);
        pk.y = pk2(acw[nt][2] + bb, acw[nt][3] + bb);
        *reinterpret_cast<uint2*>(sFinu + nt * 2048 + ch * 16 + q * 4) = pk;
      }
    }
  }
  __syncthreads();   // B6

  // ---- phase 5: coalesced writeout (2 windows per 16B) + GN partial stats ----
  {
    ushort* sFinu = (ushort*)LM;
    #pragma unroll
    for (int it = 0; it < 4; it++) {
      int seg = it * 256 + t;            // [0,1024)
      int ch = seg >> 3, r = (seg >> 1) & 3, half = seg & 1;
      const ushort* f0 = sFinu + (half * 2    ) * 2048;
      const ushort* f1 = sFinu + (half * 2 + 1) * 2048;
      uint2 a  = *reinterpret_cast<const uint2*>(f0 + ch * 16 + r * 4);
      uint2 c2 = *reinterpret_cast<const uint2*>(f1 + ch * 16 + r * 4);
      uint4 val = {a.x, a.y, c2.x, c2.y};
      *reinterpret_cast<uint4*>(attn_map + (size_t)(b * 128 + ch) * PIX
                                + (wh * 4 + r) * 128 + ww0 * 16 + half * 8) = val;
      float sv = 0.f, sv2 = 0.f;
      uint uu[4] = {val.x, val.y, val.z, val.w};
      #pragma unroll
      for (int k2 = 0; k2 < 4; k2++) {
        float fv0 = bf2f((ushort)(uu[k2] & 0xFFFFu));
        float fv1 = bf2f((ushort)(uu[k2] >> 16));
        sv += fv0 + fv1; sv2 += fv0 * fv0 + fv1 * fv1;
      }
      sv  += __shfl_xor(sv, 1);  sv  += __shfl_xor(sv, 2);  sv  += __shfl_xor(sv, 4);
      sv2 += __shfl_xor(sv2, 1); sv2 += __shfl_xor(sv2, 2); sv2 += __shfl_xor(sv2, 4);
      if ((t & 7) == 0) {
        int g = ch >> 4;
        atomicAdd(&sStat[g * 2], sv);
        atomicAdd(&sStat[g * 2 + 1], sv2);
      }
    }
  }
  __syncthreads();
  if (t < 16) atomicAdd(&stA_raw[b * 16 + t], sStat[t]);
}

// ---------------- GN + gates MFMA + LSTM update (+stats for GN2) ----------------
// (round-18; ks=0 FWg fragments hoisted above staging barrier)
__global__ __launch_bounds__(256, 4) void k_gates(
    const ushort* __restrict__ attn_map, const float* __restrict__ stA_raw,
    const float* __restrict__ gn_g, const float* __restrict__ gn_b,
    const ushort* __restrict__ FWg, const float* __restrict__ bgates,
    const float* __restrict__ c, float* __restrict__ cnext,
    ushort* __restrict__ tbuf, float* __restrict__ stB_raw)
{
  __shared__ uint sG2[32 * 66];     // [px][ch-pair dwords + 2 pad] = 8448 B
  __shared__ float sA[128], sB[128];
  __shared__ float sStat[16];
  const int t = threadIdx.x, bid = blockIdx.x;
  const int b = bid >> 9, p0 = (bid & 511) * 32;
  const int w = t >> 6, l = t & 63, q = l >> 4, r16 = l & 15;

  if (t < 128) {
    int g = t >> 4;
    const float invN = 1.f / 262144.f;
    float mu = stA_raw[b * 16 + g * 2] * invN;
    float var = stA_raw[b * 16 + g * 2 + 1] * invN - mu * mu;
    float rs = rsqrtf(var + EPSF);
    float A = rs * gn_g[t];
    sA[t] = A; sB[t] = gn_b[t] - mu * A;
  }
  if (t >= 240) sStat[t - 240] = 0.f;
  __syncthreads();

  // ---- hoisted ks=0 weight fragments (overlap with staging) ----
  Frag wg0[4][2];
  #pragma unroll
  for (int g2 = 0; g2 < 4; g2++)
    #pragma unroll
    for (int j = 0; j < 2; j++) {
      int ct = w + 4 * j + 8 * g2;
      wg0[g2][j].u4 = *reinterpret_cast<const uint4*>(FWg + ((ct * 4 + 0) * 64 + l) * 8);
    }

  // ---- staging: GN(attn) -> sG2[px][ch] (transposed) ----
  {
    int pr = t >> 2, px0 = (t & 3) * 8;
    int c0 = pr * 2;
    const ushort* ab = attn_map + (size_t)(b * 128 + c0) * PIX + p0 + px0;
    uint4 a0 = *reinterpret_cast<const uint4*>(ab);
    uint4 a1 = *reinterpret_cast<const uint4*>(ab + PIX);
    float A0 = sA[c0], B0 = sB[c0], A1 = sA[c0 + 1], B1 = sB[c0 + 1];
    uint u0[4] = {a0.x, a0.y, a0.z, a0.w};
    uint u1[4] = {a1.x, a1.y, a1.z, a1.w};
    #pragma unroll
    for (int j = 0; j < 4; j++) {
      float v0lo = bf2f((ushort)(u0[j] & 0xFFFFu)) * A0 + B0;
      float v0hi = bf2f((ushort)(u0[j] >> 16)) * A0 + B0;
      float v1lo = bf2f((ushort)(u1[j] & 0xFFFFu)) * A1 + B1;
      float v1hi = bf2f((ushort)(u1[j] >> 16)) * A1 + B1;
      sG2[(px0 + 2 * j) * 66 + pr]     = pk2(v0lo, v1lo);
      sG2[(px0 + 2 * j + 1) * 66 + pr] = pk2(v0hi, v1hi);
    }
  }

  // ---- prefetch c ----
  float4 cv[2][2];
  #pragma unroll
  for (int j = 0; j < 2; j++) {
    int ch = (w + 4 * j) * 16 + r16;
    const float* cb = c + (size_t)(b * 128 + ch) * PIX + p0 + q * 4;
    cv[j][0] = *reinterpret_cast<const float4*>(cb);
    cv[j][1] = *reinterpret_cast<const float4*>(cb + 16);
  }
  __syncthreads();

  // ---- gates GEMM: D[px][ch]; acc[gate][j][pxt], ch tile = w + 4j + 8*gate ----
  f32x4 acc[4][2][2];
  #pragma unroll
  for (int g2 = 0; g2 < 4; g2++)
    #pragma unroll
    for (int j = 0; j < 2; j++)
      #pragma unroll
      for (int pxt = 0; pxt < 2; pxt++) acc[g2][j][pxt] = (f32x4){0.f, 0.f, 0.f, 0.f};

  const ushort* sGu = (const ushort*)sG2;
  // ks = 0 (hoisted weights)
  {
    Frag af[2];
    #pragma unroll
    for (int pxt = 0; pxt < 2; pxt++)
      af[pxt].u4 = *reinterpret_cast<const uint4*>(sGu + (pxt * 16 + r16) * 132 + q * 8);
    #pragma unroll
    for (int g2 = 0; g2 < 4; g2++)
      #pragma unroll
      for (int j = 0; j < 2; j++)
        #pragma unroll
        for (int pxt = 0; pxt < 2; pxt++)
          acc[g2][j][pxt] = __builtin_amdgcn_mfma_f32_16x16x32_bf16(af[pxt].s, wg0[g2][j].s, acc[g2][j][pxt], 0, 0, 0);
  }
  #pragma unroll
  for (int ks = 1; ks < 4; ks++) {
    Frag af[2];
    #pragma unroll
    for (int pxt = 0; pxt < 2; pxt++)
      af[pxt].u4 = *reinterpret_cast<const uint4*>(sGu + (pxt * 16 + r16) * 132 + ks * 32 + q * 8);
    #pragma unroll
    for (int g2 = 0; g2 < 4; g2++) {
      #pragma unroll
      for (int j = 0; j < 2; j++) {
        int ct = w + 4 * j + 8 * g2;
        Frag bfw;
        bfw.u4 = *reinterpret_cast<const uint4*>(FWg + ((ct * 4 + ks) * 64 + l) * 8);
        #pragma unroll
        for (int pxt = 0; pxt < 2; pxt++)
          acc[g2][j][pxt] = __builtin_amdgcn_mfma_f32_16x16x32_bf16(af[pxt].s, bfw.s, acc[g2][j][pxt], 0, 0, 0);
      }
    }
  }

  // ---- LSTM epilogue: vectorized c/cnext/tbuf ----
  float gs[2] = {0.f, 0.f}, gs2[2] = {0.f, 0.f};
  #pragma unroll
  for (int j = 0; j < 2; j++) {
    int ch = (w + 4 * j) * 16 + r16;
    float bi = bgates[ch], bff = bgates[128 + ch], bog = bgates[256 + ch], bgg = bgates[384 + ch];
    #pragma unroll
    for (int pxt = 0; pxt < 2; pxt++) {
      size_t gbase = (size_t)(b * 128 + ch) * PIX + p0 + pxt * 16 + q * 4;
      const float cc[4] = {cv[j][pxt].x, cv[j][pxt].y, cv[j][pxt].z, cv[j][pxt].w};
      float cn[4], tv[4];
      #pragma unroll
      for (int r = 0; r < 4; r++) {
        float ig = fsigmoid(acc[0][j][pxt][r] + bi);
        float fg = fsigmoid(acc[1][j][pxt][r] + bff);
        float og = fsigmoid(acc[2][j][pxt][r] + bog);
        float gg = ftanh   (acc[3][j][pxt][r] + bgg);
        cn[r] = fg * cc[r] + ig * gg;
        tv[r] = og * ftanh(cn[r]);
        gs[j] += tv[r]; gs2[j] += tv[r] * tv[r];
      }
      float4 cno = {cn[0], cn[1], cn[2], cn[3]};
      *reinterpret_cast<float4*>(cnext + gbase) = cno;
      uint2 tpk;
      tpk.x = pk2(tv[0], tv[1]); tpk.y = pk2(tv[2], tv[3]);
      *reinterpret_cast<uint2*>(tbuf + gbase) = tpk;
    }
  }
  #pragma unroll
  for (int j = 0; j < 2; j++) {
    float s = gs[j], s2 = gs2[j];
    s += __shfl_xor(s, 1); s += __shfl_xor(s, 2); s += __shfl_xor(s, 4);
    s += __shfl_xor(s, 8); s += __shfl_xor(s, 16); s += __shfl_xor(s, 32);
    s2 += __shfl_xor(s2, 1); s2 += __shfl_xor(s2, 2); s2 += __shfl_xor(s2, 4);
    s2 += __shfl_xor(s2, 8); s2 += __shfl_xor(s2, 16); s2 += __shfl_xor(s2, 32);
    if (l == 0) {
      int g = w + 4 * j;
      atomicAdd(&sStat[g * 2], s);
      atomicAdd(&sStat[g * 2 + 1], s2);
    }
  }
  __syncthreads();
  if (t < 16) atomicAdd(&stB_raw[b * 16 + t], sStat[t]);
}

// ---------------- hnext = GN2(tbuf), inline stats finalize ----------------
__global__ __launch_bounds__(256) void k_gnout(
    const ushort* __restrict__ tbuf, const float* __restrict__ stB_raw,
    const float* __restrict__ gn_g, const float* __restrict__ gn_b,
    float* __restrict__ hnext)
{
  size_t idx = ((size_t)blockIdx.x * 256 + threadIdx.x) * 8;
  if (idx >= (size_t)16777216) return;
  int chrow = (int)(idx >> 14);
  int b = chrow >> 7, ch = chrow & 127, g = ch >> 4;
  const float invN = 1.f / 262144.f;
  float mu = stB_raw[b * 16 + g * 2] * invN;
  float var = stB_raw[b * 16 + g * 2 + 1] * invN - mu * mu;
  float rstd = rsqrtf(var + EPSF);
  float A = gn_g[ch] * rstd, Bv = gn_b[ch] - mu * A;
  uint4 u = *reinterpret_cast<const uint4*>(tbuf + idx);
  float4 o0, o1;
  o0.x = bf2f((ushort)(u.x & 0xFFFFu)) * A + Bv;
  o0.y = bf2f((ushort)(u.x >> 16)) * A + Bv;
  o0.z = bf2f((ushort)(u.y & 0xFFFFu)) * A + Bv;
  o0.w = bf2f((ushort)(u.y >> 16)) * A + Bv;
  o1.x = bf2f((ushort)(u.z & 0xFFFFu)) * A + Bv;
  o1.y = bf2f((ushort)(u.z >> 16)) * A + Bv;
  o1.z = bf2f((ushort)(u.w & 0xFFFFu)) * A + Bv;
  o1.w = bf2f((ushort)(u.w >> 16)) * A + Bv;
  *reinterpret_cast<float4*>(hnext + idx) = o0;
  *reinterpret_cast<float4*>(hnext + idx + 4) = o1;
}

extern "C" void kernel_launch(void* const* d_in, const int* in_sizes, int n_in,
                              void* d_out, int out_size, void* d_ws, size_t ws_size,
                              hipStream_t stream) {
  (void)in_sizes; (void)n_in; (void)out_size; (void)ws_size;
  const float* x      = (const float*)d_in[0];
  const float* h      = (const float*)d_in[1];
  const float* c      = (const float*)d_in[2];
  const float* Wproj  = (const float*)d_in[3];
  const float* bproj  = (const float*)d_in[4];
  const float* ln_g   = (const float*)d_in[5];
  const float* ln_b   = (const float*)d_in[6];
  const float* Wqkv   = (const float*)d_in[7];
  const float* bqkv   = (const float*)d_in[8];
  const float* Wo     = (const float*)d_in[9];
  const float* bo     = (const float*)d_in[10];
  const float* Wgates = (const float*)d_in[11];
  const float* bgates = (const float*)d_in[12];
  const float* gn_g   = (const float*)d_in[13];
  const float* gn_b   = (const float*)d_in[14];

  float* out = (float*)d_out;
  float* hnext = out;
  float* cnext = out + 16777216;

  char* W = (char*)d_ws;
  ushort* attn = (ushort*)W;                          // 32 MB bf16
  ushort* tbuf = (ushort*)(W + 33554432);             // 32 MB bf16
  size_t off = 67108864;
  ushort* FWp = (ushort*)(W + off); off += 49152;
  ushort* FWq = (ushort*)(W + off); off += 98304;
  ushort* FWo = (ushort*)(W + off); off += 32768;
  ushort* FWg = (ushort*)(W + off); off += 131072;
  float* stA_raw = (float*)(W + off); off += 512;
  float* stB_raw = (float*)(W + off); off += 512;
  float* Sarr    = (float*)(W + off); off += 1536;
  float* Tbarr   = (float*)(W + off); off += 1536;

  hipMemsetAsync(stA_raw, 0, 1024, stream);

  k_prep<<<78, 256, 0, stream>>>(Wproj, Wqkv, Wo, Wgates, ln_g, ln_b, bqkv,
                                 FWp, FWq, FWo, FWg, Sarr, Tbarr);

  k_attn<<<2048, 256, 0, stream>>>(x, h, FWp, bproj, FWq, Sarr, Tbarr,
                                   FWo, bo, attn, stA_raw);
  k_gates<<<4096, 256, 0, stream>>>(attn, stA_raw, gn_g, gn_b, FWg, bgates,
                                    c, cnext, tbuf, stB_raw);
  k_gnout<<<8192, 256, 0, stream>>>(tbuf, stB_raw, gn_g, gn_b, hnext);
}

// Round 20
// 186.892 us; speedup vs baseline: 1.1556x; 1.0046x over previous
//
#include <hip/hip_runtime.h>
#include <math.h>

typedef unsigned int uint;
typedef unsigned short ushort;
typedef short s16x8 __attribute__((ext_vector_type(8)));
typedef float f32x4 __attribute__((ext_vector_type(4)));

#define PIX 16384
#define EPSF 1e-5f

__device__ __forceinline__ ushort f2bf(float f) {
  union { float f; uint u; } v; v.f = f;
  uint u = v.u;
  uint r = (u + 0x7FFFu + ((u >> 16) & 1u)) >> 16;
  return (ushort)r;
}
__device__ __forceinline__ float bf2f(ushort h) {
  union { uint u; float f; } v; v.u = ((uint)h) << 16;
  return v.f;
}
__device__ __forceinline__ uint pk2(float a, float b) {
  return (uint)f2bf(a) | ((uint)f2bf(b) << 16);
}
__device__ __forceinline__ float frcp(float x) { return __builtin_amdgcn_rcpf(x); }
__device__ __forceinline__ float fsigmoid(float v) { return frcp(1.f + __expf(-v)); }
__device__ __forceinline__ float ftanh(float v) { return 1.f - 2.f * frcp(__expf(2.f * v) + 1.f); }

union Frag { uint4 u4; uint u[4]; s16x8 s; };

// ---------------- merged weight fragment prep (+ folded-LN S/Tb vectors) ----------------
// frag (mt, ks): lane l elem j = W[mt*16 + (l&15)][ks*32 + (l>>4)*8 + j]
// FWq columns pre-scaled by ln_g. Tail threads (idx>=19456) compute Sarr/Tbarr.
__global__ void k_prep(const float* __restrict__ Wp, const float* __restrict__ Wq,
                       const float* __restrict__ Wo, const float* __restrict__ Wg,
                       const float* __restrict__ ln_g, const float* __restrict__ ln_b,
                       const float* __restrict__ bqkv,
                       ushort* __restrict__ FWp, ushort* __restrict__ FWq,
                       ushort* __restrict__ FWo, ushort* __restrict__ FWg,
                       float* __restrict__ Sarr, float* __restrict__ Tbarr) {
  int idx = blockIdx.x * 256 + threadIdx.x;   // [0, 19968)
  if (idx >= 19456) {
    int o = idx - 19456;
    if (o >= 384) return;
    float S = 0.f, T = 0.f;
    const float* wr = Wq + (size_t)o * 128;
    for (int i = 0; i < 128; i++) {
      float wv = wr[i];
      S = fmaf(wv, ln_g[i], S);
      T = fmaf(wv, ln_b[i], T);
    }
    Sarr[o] = S;
    Tbarr[o] = T + bqkv[o];
    return;
  }
  const float* W; ushort* F; int KS, ldw, rel; bool scale = false;
  if (idx < 3072)       { W = Wp; F = FWp; KS = 6; ldw = 192; rel = idx; }
  else if (idx < 9216)  { W = Wq; F = FWq; KS = 4; ldw = 128; rel = idx - 3072; scale = true; }
  else if (idx < 11264) { W = Wo; F = FWo; KS = 4; ldw = 128; rel = idx - 9216; }
  else                  { W = Wg; F = FWg; KS = 4; ldw = 128; rel = idx - 11264; }
  int l = rel & 63, rest = rel >> 6;
  int ks = rest % KS, mt = rest / KS;
  int col = ks * 32 + (l >> 4) * 8;
  const float* src = W + (size_t)(mt * 16 + (l & 15)) * ldw + col;
  float g[8] = {1.f, 1.f, 1.f, 1.f, 1.f, 1.f, 1.f, 1.f};
  if (scale) {
    #pragma unroll
    for (int j = 0; j < 8; j++) g[j] = ln_g[col + j];
  }
  uint4 v;
  v.x = pk2(src[0] * g[0], src[1] * g[1]);
  v.y = pk2(src[2] * g[2], src[3] * g[3]);
  v.z = pk2(src[4] * g[4], src[5] * g[5]);
  v.w = pk2(src[6] * g[6], src[7] * g[7]);
  *reinterpret_cast<uint4*>(F + (size_t)rel * 8) = v;
}

// ---------------- fused proj + (folded LN) + window MHSA + Wo (+GN stats) ----------------
// (round-19 structure; additional hoists: FWq mi=0,1 above B3, FWoT above B5)
__global__ __launch_bounds__(256, 3) void k_attn(
    const float* __restrict__ x, const float* __restrict__ h,
    const ushort* __restrict__ FWp, const float* __restrict__ bproj,
    const ushort* __restrict__ FWq, const float* __restrict__ Sarr,
    const float* __restrict__ Tbarr,
    const ushort* __restrict__ FWoT, const float* __restrict__ bo,
    ushort* __restrict__ attn_map, float* __restrict__ stA_raw)
{
  __shared__ __align__(16) char LM[51200];
  __shared__ float sSum[64], sSum2[64];
  __shared__ float sStat[16];

  const int t = threadIdx.x;
  const int bid = blockIdx.x;
  const int b = bid >> 8, wh = (bid >> 3) & 31, ww0 = bid & 7;
  const int w = t >> 6, l = t & 63, q = l >> 4, r16 = l & 15;

  uint* sInP = (uint*)LM;            // [96][68] dwords (26112 B)
  ushort* sXn = (ushort*)LM;         // [64][136]

  if (t < 64) { sSum[t] = 0.f; sSum2[t] = 0.f; }
  if (t < 16) sStat[t] = 0.f;

  // ---- hoisted phase-1 weight fragments: issue before staging barrier ----
  Frag wpf[2][6];
  #pragma unroll
  for (int mi = 0; mi < 2; mi++)
    #pragma unroll
    for (int ks = 0; ks < 6; ks++)
      wpf[mi][ks].u4 = *reinterpret_cast<const uint4*>(FWp + (((w + mi * 4) * 6 + ks) * 64 + l) * 8);

  // ---- phase 0: stage concat(x,h) -> sInP[chp][col], col = window*16 + token ----
  {
    const float* xb = x + (size_t)b * 64 * PIX;
    const float* hb = h + (size_t)b * 128 * PIX;
    #pragma unroll
    for (int it = 0; it < 6; it++) {
      int item = it * 256 + t;                 // [0,1536)
      int wv = item & 3, r = (item >> 2) & 3, chp = item >> 4;
      int ch0 = chp * 2;
      int gpix = (wh * 4 + r) * 128 + ww0 * 16 + wv * 4;
      float4 a, c2;
      if (ch0 < 64) {
        a  = *reinterpret_cast<const float4*>(xb + (size_t)ch0 * PIX + gpix);
        c2 = *reinterpret_cast<const float4*>(xb + (size_t)(ch0 + 1) * PIX + gpix);
      } else {
        a  = *reinterpret_cast<const float4*>(hb + (size_t)(ch0 - 64) * PIX + gpix);
        c2 = *reinterpret_cast<const float4*>(hb + (size_t)(ch0 - 63) * PIX + gpix);
      }
      uint4 pkd;
      pkd.x = pk2(a.x, c2.x); pkd.y = pk2(a.y, c2.y);
      pkd.z = pk2(a.z, c2.z); pkd.w = pk2(a.w, c2.w);
      *reinterpret_cast<uint4*>(sInP + chp * 68 + wv * 16 + r * 4) = pkd;
    }
  }
  __syncthreads();   // B1

  // ---- phase 1: proj MFMA. wave w owns mt in {w, w+4}; nt = window 0..3 ----
  f32x4 acc1[2][4];
  {
    #pragma unroll
    for (int mi = 0; mi < 2; mi++)
      #pragma unroll
      for (int nt = 0; nt < 4; nt++) acc1[mi][nt] = (f32x4){0.f, 0.f, 0.f, 0.f};
    for (int ks = 0; ks < 6; ks++) {
      Frag bf[4];
      #pragma unroll
      for (int nt = 0; nt < 4; nt++)
        #pragma unroll
        for (int s = 0; s < 4; s++)
          bf[nt].u[s] = sInP[(ks * 16 + q * 4 + s) * 68 + nt * 16 + r16];
      #pragma unroll
      for (int mi = 0; mi < 2; mi++) {
        #pragma unroll
        for (int nt = 0; nt < 4; nt++)
          acc1[mi][nt] = __builtin_amdgcn_mfma_f32_16x16x32_bf16(wpf[mi][ks].s, bf[nt].s, acc1[mi][nt], 0, 0, 0);
      }
    }
  }
  __syncthreads();   // B2: all sInP reads done; sXn overlays

  // ---- phase 1b: bias, pack raw p -> sXn, per-token LN stats (fp32) ----
  {
    float pst[4] = {0.f, 0.f, 0.f, 0.f}, pst2[4] = {0.f, 0.f, 0.f, 0.f};
    #pragma unroll
    for (int mi = 0; mi < 2; mi++) {
      int o0 = (w + mi * 4) * 16 + q * 4;
      const float4 bv = *reinterpret_cast<const float4*>(bproj + o0);
      #pragma unroll
      for (int nt = 0; nt < 4; nt++) {
        float v0 = acc1[mi][nt][0] + bv.x, v1 = acc1[mi][nt][1] + bv.y;
        float v2 = acc1[mi][nt][2] + bv.z, v3 = acc1[mi][nt][3] + bv.w;
        uint2 pk; pk.x = pk2(v0, v1); pk.y = pk2(v2, v3);
        *reinterpret_cast<uint2*>(sXn + (nt * 16 + r16) * 136 + o0) = pk;
        pst[nt]  += v0 + v1 + v2 + v3;
        pst2[nt] += v0 * v0 + v1 * v1 + v2 * v2 + v3 * v3;
      }
    }
    #pragma unroll
    for (int nt = 0; nt < 4; nt++) {
      float s = pst[nt], s2 = pst2[nt];
      s  += __shfl_xor(s, 16);  s  += __shfl_xor(s, 32);
      s2 += __shfl_xor(s2, 16); s2 += __shfl_xor(s2, 32);
      if (q == 0) {
        atomicAdd(&sSum[nt * 16 + r16], s);
        atomicAdd(&sSum2[nt * 16 + r16], s2);
      }
    }
  }

  // ---- hoisted FWq fragments for Q/K tiles mi=0,1: issue before B3 ----
  Frag wq01[2][4];
  #pragma unroll
  for (int mi = 0; mi < 2; mi++)
    #pragma unroll
    for (int ks = 0; ks < 4; ks++)
      wq01[mi][ks].u4 = *reinterpret_cast<const uint4*>(FWq + (((w + mi * 4) * 4 + ks) * 64 + l) * 8);
  __syncthreads();   // B3: sXn + stats ready

  // ---- phase 2: hoist xn frags; QK GEMM -> slices; V GEMM held in regs ----
  float rstd_[4], mr_[4];
  f32x4 accV[2][4];
  {
    Frag bfh[4][4];   // [ks][nt] — all sXn reads happen here
    #pragma unroll
    for (int ks = 0; ks < 4; ks++)
      #pragma unroll
      for (int nt = 0; nt < 4; nt++)
        bfh[ks][nt].u4 = *reinterpret_cast<const uint4*>(sXn + (nt * 16 + r16) * 136 + ks * 32 + q * 8);

    #pragma unroll
    for (int nt = 0; nt < 4; nt++) {
      int tok = nt * 16 + r16;
      float mu = sSum[tok] * 0.0078125f;
      float var = sSum2[tok] * 0.0078125f - mu * mu;
      rstd_[nt] = rsqrtf(var + EPSF);
      mr_[nt] = -mu * rstd_[nt];
    }

    ushort* sQKu = (ushort*)(LM + 17408);
    #pragma unroll
    for (int mi = 0; mi < 4; mi++) {        // Q,K tiles: mt = w + mi*4 < 16
      int mt = w + mi * 4;
      f32x4 accq[4];
      #pragma unroll
      for (int nt = 0; nt < 4; nt++) accq[nt] = (f32x4){0.f, 0.f, 0.f, 0.f};
      #pragma unroll
      for (int ks = 0; ks < 4; ks++) {
        Frag af;
        if (mi < 2) af = wq01[mi][ks];
        else af.u4 = *reinterpret_cast<const uint4*>(FWq + ((mt * 4 + ks) * 64 + l) * 8);
        #pragma unroll
        for (int nt = 0; nt < 4; nt++)
          accq[nt] = __builtin_amdgcn_mfma_f32_16x16x32_bf16(af.s, bfh[ks][nt].s, accq[nt], 0, 0, 0);
      }
      int oo = mt * 16 + q * 4;
      const float4 S4  = *reinterpret_cast<const float4*>(Sarr + oo);
      const float4 Tb4 = *reinterpret_cast<const float4*>(Tbarr + oo);
      #pragma unroll
      for (int nt = 0; nt < 4; nt++) {
        float v0 = fmaf(rstd_[nt], accq[nt][0], fmaf(mr_[nt], S4.x, Tb4.x));
        float v1 = fmaf(rstd_[nt], accq[nt][1], fmaf(mr_[nt], S4.y, Tb4.y));
        float v2 = fmaf(rstd_[nt], accq[nt][2], fmaf(mr_[nt], S4.z, Tb4.z));
        float v3 = fmaf(rstd_[nt], accq[nt][3], fmaf(mr_[nt], S4.w, Tb4.w));
        uint2 pk; pk.x = pk2(v0, v1); pk.y = pk2(v2, v3);
        *reinterpret_cast<uint2*>(sQKu + nt * 4224 + r16 * 264 + oo) = pk;
      }
    }
    #pragma unroll
    for (int mi = 0; mi < 2; mi++) {        // V tiles: mt = w+16, w+20
      int mt = w + 16 + mi * 4;
      #pragma unroll
      for (int nt = 0; nt < 4; nt++) accV[mi][nt] = (f32x4){0.f, 0.f, 0.f, 0.f};
      #pragma unroll
      for (int ks = 0; ks < 4; ks++) {
        Frag af;
        af.u4 = *reinterpret_cast<const uint4*>(FWq + ((mt * 4 + ks) * 64 + l) * 8);
        #pragma unroll
        for (int nt = 0; nt < 4; nt++)
          accV[mi][nt] = __builtin_amdgcn_mfma_f32_16x16x32_bf16(af.s, bfh[ks][nt].s, accV[mi][nt], 0, 0, 0);
      }
    }
  }
  __syncthreads();   // B4: all waves' sXn reads drained; R0 free for V

  // ---- phase 2b: V epilogue -> R0 [0,16384) ----
  {
    ushort* sVu = (ushort*)LM;
    #pragma unroll
    for (int mi = 0; mi < 2; mi++) {
      int mt = w + 16 + mi * 4;
      int oo = mt * 16 + q * 4;
      const float4 S4  = *reinterpret_cast<const float4*>(Sarr + oo);
      const float4 Tb4 = *reinterpret_cast<const float4*>(Tbarr + oo);
      #pragma unroll
      for (int nt = 0; nt < 4; nt++) {
        float v0 = fmaf(rstd_[nt], accV[mi][nt][0], fmaf(mr_[nt], S4.x, Tb4.x));
        float v1 = fmaf(rstd_[nt], accV[mi][nt][1], fmaf(mr_[nt], S4.y, Tb4.y));
        float v2 = fmaf(rstd_[nt], accV[mi][nt][2], fmaf(mr_[nt], S4.z, Tb4.z));
        float v3 = fmaf(rstd_[nt], accV[mi][nt][3], fmaf(mr_[nt], S4.w, Tb4.w));
        ushort* vd = sVu + nt * 2048 + (oo - 256) * 16 + r16;
        vd[0] = f2bf(v0); vd[16] = f2bf(v1); vd[32] = f2bf(v2); vd[48] = f2bf(v3);
      }
    }
  }
  __syncthreads();   // B4b: V visible to all waves

  // ---- phase 3: scores + softmax + PV, wave = window w ----
  {
    const float scale = 0.17677669529663687f;
    ushort* sQKw = (ushort*)(LM + 17408 + w * 8448);
    ushort* sPw  = sQKw;
    Frag af4[4], bf4[4];
    #pragma unroll
    for (int hd = 0; hd < 4; hd++) {
      af4[hd].u4 = *reinterpret_cast<const uint4*>(sQKw + r16 * 264 + hd * 32 + q * 8);
      bf4[hd].u4 = *reinterpret_cast<const uint4*>(sQKw + r16 * 264 + 128 + hd * 32 + q * 8);
    }
    #pragma unroll
    for (int hd = 0; hd < 4; hd++) {
      if (l < 32) {
        int row = l >> 1, hz = l & 1;
        uint4 z = {0u, 0u, 0u, 0u};
        *reinterpret_cast<uint4*>(sPw + hd * 512 + row * 32 + 16 + hz * 8) = z;
      }
    }
    f32x4 sc[4];
    #pragma unroll
    for (int hd = 0; hd < 4; hd++) {
      f32x4 z4 = (f32x4){0.f, 0.f, 0.f, 0.f};
      sc[hd] = __builtin_amdgcn_mfma_f32_16x16x32_bf16(af4[hd].s, bf4[hd].s, z4, 0, 0, 0);
    }
    #pragma unroll
    for (int hd = 0; hd < 4; hd++) {
      ushort* pd = sPw + hd * 512 + (q * 4) * 32 + r16;
      #pragma unroll
      for (int r = 0; r < 4; r++) {
        float sv = sc[hd][r] * scale;
        float mx = sv;
        mx = fmaxf(mx, __shfl_xor(mx, 1));
        mx = fmaxf(mx, __shfl_xor(mx, 2));
        mx = fmaxf(mx, __shfl_xor(mx, 4));
        mx = fmaxf(mx, __shfl_xor(mx, 8));
        float e = __expf(sv - mx);
        float sm = e;
        sm += __shfl_xor(sm, 1); sm += __shfl_xor(sm, 2);
        sm += __shfl_xor(sm, 4); sm += __shfl_xor(sm, 8);
        pd[r * 32] = f2bf(e * frcp(sm));
      }
    }
    // PV -> sO at slice[4096,8448); V from R0
    ushort* sOw = sQKw + 2048;               // +4096 B
    ushort* sVw = (ushort*)LM + w * 2048;    // window w's V (4096 B)
    #pragma unroll
    for (int hd = 0; hd < 4; hd++) {
      Frag pa;
      pa.u4 = *reinterpret_cast<const uint4*>(sPw + hd * 512 + r16 * 32 + q * 8);
      #pragma unroll
      for (int nt2 = 0; nt2 < 2; nt2++) {
        int ch = hd * 32 + nt2 * 16 + r16;
        int off = (q < 2) ? q * 8 : 0;
        Frag vf;
        vf.u4 = *reinterpret_cast<const uint4*>(sVw + ch * 16 + off);
        f32x4 z4 = (f32x4){0.f, 0.f, 0.f, 0.f};
        f32x4 o4 = __builtin_amdgcn_mfma_f32_16x16x32_bf16(pa.s, vf.s, z4, 0, 0, 0);
        ushort* od = sOw + (q * 4) * 136 + ch;
        od[0] = f2bf(o4[0]); od[136] = f2bf(o4[1]);
        od[272] = f2bf(o4[2]); od[408] = f2bf(o4[3]);
      }
    }
  }

  // ---- hoisted FWoT fragments: issue before B5 (hide under phase-3 tail) ----
  Frag wof[2][4];
  #pragma unroll
  for (int mi2 = 0; mi2 < 2; mi2++)
    #pragma unroll
    for (int ks = 0; ks < 4; ks++)
      wof[mi2][ks].u4 = *reinterpret_cast<const uint4*>(FWoT + (((w + mi2 * 4) * 4 + ks) * 64 + l) * 8);
  __syncthreads();   // B5: all sO ready; R0 (V) dead -> sFin

  // ---- phase 4: Wo MFMA. wave w owns ntg in {w, w+4}; nt = window ----
  {
    ushort* sFinu = (ushort*)LM;
    Frag a4[4][4];
    #pragma unroll
    for (int nt = 0; nt < 4; nt++) {
      ushort* sOnt = (ushort*)(LM + 17408 + nt * 8448 + 4096);
      #pragma unroll
      for (int ks = 0; ks < 4; ks++)
        a4[nt][ks].u4 = *reinterpret_cast<const uint4*>(sOnt + r16 * 136 + ks * 32 + q * 8);
    }
    #pragma unroll
    for (int mi2 = 0; mi2 < 2; mi2++) {
      int ntg = w + mi2 * 4;
      f32x4 acw[4];
      #pragma unroll
      for (int nt = 0; nt < 4; nt++) acw[nt] = (f32x4){0.f, 0.f, 0.f, 0.f};
      #pragma unroll
      for (int ks = 0; ks < 4; ks++) {
        #pragma unroll
        for (int nt = 0; nt < 4; nt++)
          acw[nt] = __builtin_amdgcn_mfma_f32_16x16x32_bf16(a4[nt][ks].s, wof[mi2][ks].s, acw[nt], 0, 0, 0);
      }
      int ch = ntg * 16 + r16;
      float bb = bo[ch];
      #pragma unroll
      for (int nt = 0; nt < 4; nt++) {
        uint2 pk;
        pk.x = pk2(acw[nt][0] + bb, acw[nt][1] + bb);
        pk.y = pk2(acw[nt][2] + bb, acw[nt][3] + bb);
        *reinterpret_cast<uint2*>(sFinu + nt * 2048 + ch * 16 + q * 4) = pk;
      }
    }
  }
  __syncthreads();   // B6

  // ---- phase 5: coalesced writeout (2 windows per 16B) + GN partial stats ----
  {
    ushort* sFinu = (ushort*)LM;
    #pragma unroll
    for (int it = 0; it < 4; it++) {
      int seg = it * 256 + t;            // [0,1024)
      int ch = seg >> 3, r = (seg >> 1) & 3, half = seg & 1;
      const ushort* f0 = sFinu + (half * 2    ) * 2048;
      const ushort* f1 = sFinu + (half * 2 + 1) * 2048;
      uint2 a  = *reinterpret_cast<const uint2*>(f0 + ch * 16 + r * 4);
      uint2 c2 = *reinterpret_cast<const uint2*>(f1 + ch * 16 + r * 4);
      uint4 val = {a.x, a.y, c2.x, c2.y};
      *reinterpret_cast<uint4*>(attn_map + (size_t)(b * 128 + ch) * PIX
                                + (wh * 4 + r) * 128 + ww0 * 16 + half * 8) = val;
      float sv = 0.f, sv2 = 0.f;
      uint uu[4] = {val.x, val.y, val.z, val.w};
      #pragma unroll
      for (int k2 = 0; k2 < 4; k2++) {
        float fv0 = bf2f((ushort)(uu[k2] & 0xFFFFu));
        float fv1 = bf2f((ushort)(uu[k2] >> 16));
        sv += fv0 + fv1; sv2 += fv0 * fv0 + fv1 * fv1;
      }
      sv  += __shfl_xor(sv, 1);  sv  += __shfl_xor(sv, 2);  sv  += __shfl_xor(sv, 4);
      sv2 += __shfl_xor(sv2, 1); sv2 += __shfl_xor(sv2, 2); sv2 += __shfl_xor(sv2, 4);
      if ((t & 7) == 0) {
        int g = ch >> 4;
        atomicAdd(&sStat[g * 2], sv);
        atomicAdd(&sStat[g * 2 + 1], sv2);
      }
    }
  }
  __syncthreads();
  if (t < 16) atomicAdd(&stA_raw[b * 16 + t], sStat[t]);
}

// ---------------- GN + gates MFMA + LSTM update (+stats for GN2) ----------------
// (round-19; ks=0 FWg fragments hoisted above staging barrier)
__global__ __launch_bounds__(256, 4) void k_gates(
    const ushort* __restrict__ attn_map, const float* __restrict__ stA_raw,
    const float* __restrict__ gn_g, const float* __restrict__ gn_b,
    const ushort* __restrict__ FWg, const float* __restrict__ bgates,
    const float* __restrict__ c, float* __restrict__ cnext,
    ushort* __restrict__ tbuf, float* __restrict__ stB_raw)
{
  __shared__ uint sG2[32 * 66];     // [px][ch-pair dwords + 2 pad] = 8448 B
  __shared__ float sA[128], sB[128];
  __shared__ float sStat[16];
  const int t = threadIdx.x, bid = blockIdx.x;
  const int b = bid >> 9, p0 = (bid & 511) * 32;
  const int w = t >> 6, l = t & 63, q = l >> 4, r16 = l & 15;

  if (t < 128) {
    int g = t >> 4;
    const float invN = 1.f / 262144.f;
    float mu = stA_raw[b * 16 + g * 2] * invN;
    float var = stA_raw[b * 16 + g * 2 + 1] * invN - mu * mu;
    float rs = rsqrtf(var + EPSF);
    float A = rs * gn_g[t];
    sA[t] = A; sB[t] = gn_b[t] - mu * A;
  }
  if (t >= 240) sStat[t - 240] = 0.f;
  __syncthreads();

  // ---- hoisted ks=0 weight fragments (overlap with staging) ----
  Frag wg0[4][2];
  #pragma unroll
  for (int g2 = 0; g2 < 4; g2++)
    #pragma unroll
    for (int j = 0; j < 2; j++) {
      int ct = w + 4 * j + 8 * g2;
      wg0[g2][j].u4 = *reinterpret_cast<const uint4*>(FWg + ((ct * 4 + 0) * 64 + l) * 8);
    }

  // ---- staging: GN(attn) -> sG2[px][ch] (transposed) ----
  {
    int pr = t >> 2, px0 = (t & 3) * 8;
    int c0 = pr * 2;
    const ushort* ab = attn_map + (size_t)(b * 128 + c0) * PIX + p0 + px0;
    uint4 a0 = *reinterpret_cast<const uint4*>(ab);
    uint4 a1 = *reinterpret_cast<const uint4*>(ab + PIX);
    float A0 = sA[c0], B0 = sB[c0], A1 = sA[c0 + 1], B1 = sB[c0 + 1];
    uint u0[4] = {a0.x, a0.y, a0.z, a0.w};
    uint u1[4] = {a1.x, a1.y, a1.z, a1.w};
    #pragma unroll
    for (int j = 0; j < 4; j++) {
      float v0lo = bf2f((ushort)(u0[j] & 0xFFFFu)) * A0 + B0;
      float v0hi = bf2f((ushort)(u0[j] >> 16)) * A0 + B0;
      float v1lo = bf2f((ushort)(u1[j] & 0xFFFFu)) * A1 + B1;
      float v1hi = bf2f((ushort)(u1[j] >> 16)) * A1 + B1;
      sG2[(px0 + 2 * j) * 66 + pr]     = pk2(v0lo, v1lo);
      sG2[(px0 + 2 * j + 1) * 66 + pr] = pk2(v0hi, v1hi);
    }
  }

  // ---- prefetch c ----
  float4 cv[2][2];
  #pragma unroll
  for (int j = 0; j < 2; j++) {
    int ch = (w + 4 * j) * 16 + r16;
    const float* cb = c + (size_t)(b * 128 + ch) * PIX + p0 + q * 4;
    cv[j][0] = *reinterpret_cast<const float4*>(cb);
    cv[j][1] = *reinterpret_cast<const float4*>(cb + 16);
  }
  __syncthreads();

  // ---- gates GEMM: D[px][ch]; acc[gate][j][pxt], ch tile = w + 4j + 8*gate ----
  f32x4 acc[4][2][2];
  #pragma unroll
  for (int g2 = 0; g2 < 4; g2++)
    #pragma unroll
    for (int j = 0; j < 2; j++)
      #pragma unroll
      for (int pxt = 0; pxt < 2; pxt++) acc[g2][j][pxt] = (f32x4){0.f, 0.f, 0.f, 0.f};

  const ushort* sGu = (const ushort*)sG2;
  // ks = 0 (hoisted weights)
  {
    Frag af[2];
    #pragma unroll
    for (int pxt = 0; pxt < 2; pxt++)
      af[pxt].u4 = *reinterpret_cast<const uint4*>(sGu + (pxt * 16 + r16) * 132 + q * 8);
    #pragma unroll
    for (int g2 = 0; g2 < 4; g2++)
      #pragma unroll
      for (int j = 0; j < 2; j++)
        #pragma unroll
        for (int pxt = 0; pxt < 2; pxt++)
          acc[g2][j][pxt] = __builtin_amdgcn_mfma_f32_16x16x32_bf16(af[pxt].s, wg0[g2][j].s, acc[g2][j][pxt], 0, 0, 0);
  }
  #pragma unroll
  for (int ks = 1; ks < 4; ks++) {
    Frag af[2];
    #pragma unroll
    for (int pxt = 0; pxt < 2; pxt++)
      af[pxt].u4 = *reinterpret_cast<const uint4*>(sGu + (pxt * 16 + r16) * 132 + ks * 32 + q * 8);
    #pragma unroll
    for (int g2 = 0; g2 < 4; g2++) {
      #pragma unroll
      for (int j = 0; j < 2; j++) {
        int ct = w + 4 * j + 8 * g2;
        Frag bfw;
        bfw.u4 = *reinterpret_cast<const uint4*>(FWg + ((ct * 4 + ks) * 64 + l) * 8);
        #pragma unroll
        for (int pxt = 0; pxt < 2; pxt++)
          acc[g2][j][pxt] = __builtin_amdgcn_mfma_f32_16x16x32_bf16(af[pxt].s, bfw.s, acc[g2][j][pxt], 0, 0, 0);
      }
    }
  }

  // ---- LSTM epilogue: vectorized c/cnext/tbuf ----
  float gs[2] = {0.f, 0.f}, gs2[2] = {0.f, 0.f};
  #pragma unroll
  for (int j = 0; j < 2; j++) {
    int ch = (w + 4 * j) * 16 + r16;
    float bi = bgates[ch], bff = bgates[128 + ch], bog = bgates[256 + ch], bgg = bgates[384 + ch];
    #pragma unroll
    for (int pxt = 0; pxt < 2; pxt++) {
      size_t gbase = (size_t)(b * 128 + ch) * PIX + p0 + pxt * 16 + q * 4;
      const float cc[4] = {cv[j][pxt].x, cv[j][pxt].y, cv[j][pxt].z, cv[j][pxt].w};
      float cn[4], tv[4];
      #pragma unroll
      for (int r = 0; r < 4; r++) {
        float ig = fsigmoid(acc[0][j][pxt][r] + bi);
        float fg = fsigmoid(acc[1][j][pxt][r] + bff);
        float og = fsigmoid(acc[2][j][pxt][r] + bog);
        float gg = ftanh   (acc[3][j][pxt][r] + bgg);
        cn[r] = fg * cc[r] + ig * gg;
        tv[r] = og * ftanh(cn[r]);
        gs[j] += tv[r]; gs2[j] += tv[r] * tv[r];
      }
      float4 cno = {cn[0], cn[1], cn[2], cn[3]};
      *reinterpret_cast<float4*>(cnext + gbase) = cno;
      uint2 tpk;
      tpk.x = pk2(tv[0], tv[1]); tpk.y = pk2(tv[2], tv[3]);
      *reinterpret_cast<uint2*>(tbuf + gbase) = tpk;
    }
  }
  #pragma unroll
  for (int j = 0; j < 2; j++) {
    float s = gs[j], s2 = gs2[j];
    s += __shfl_xor(s, 1); s += __shfl_xor(s, 2); s += __shfl_xor(s, 4);
    s += __shfl_xor(s, 8); s += __shfl_xor(s, 16); s += __shfl_xor(s, 32);
    s2 += __shfl_xor(s2, 1); s2 += __shfl_xor(s2, 2); s2 += __shfl_xor(s2, 4);
    s2 += __shfl_xor(s2, 8); s2 += __shfl_xor(s2, 16); s2 += __shfl_xor(s2, 32);
    if (l == 0) {
      int g = w + 4 * j;
      atomicAdd(&sStat[g * 2], s);
      atomicAdd(&sStat[g * 2 + 1], s2);
    }
  }
  __syncthreads();
  if (t < 16) atomicAdd(&stB_raw[b * 16 + t], sStat[t]);
}

// ---------------- hnext = GN2(tbuf), inline stats finalize ----------------
__global__ __launch_bounds__(256) void k_gnout(
    const ushort* __restrict__ tbuf, const float* __restrict__ stB_raw,
    const float* __restrict__ gn_g, const float* __restrict__ gn_b,
    float* __restrict__ hnext)
{
  size_t idx = ((size_t)blockIdx.x * 256 + threadIdx.x) * 8;
  if (idx >= (size_t)16777216) return;
  int chrow = (int)(idx >> 14);
  int b = chrow >> 7, ch = chrow & 127, g = ch >> 4;
  const float invN = 1.f / 262144.f;
  float mu = stB_raw[b * 16 + g * 2] * invN;
  float var = stB_raw[b * 16 + g * 2 + 1] * invN - mu * mu;
  float rstd = rsqrtf(var + EPSF);
  float A = gn_g[ch] * rstd, Bv = gn_b[ch] - mu * A;
  uint4 u = *reinterpret_cast<const uint4*>(tbuf + idx);
  float4 o0, o1;
  o0.x = bf2f((ushort)(u.x & 0xFFFFu)) * A + Bv;
  o0.y = bf2f((ushort)(u.x >> 16)) * A + Bv;
  o0.z = bf2f((ushort)(u.y & 0xFFFFu)) * A + Bv;
  o0.w = bf2f((ushort)(u.y >> 16)) * A + Bv;
  o1.x = bf2f((ushort)(u.z & 0xFFFFu)) * A + Bv;
  o1.y = bf2f((ushort)(u.z >> 16)) * A + Bv;
  o1.z = bf2f((ushort)(u.w & 0xFFFFu)) * A + Bv;
  o1.w = bf2f((ushort)(u.w >> 16)) * A + Bv;
  *reinterpret_cast<float4*>(hnext + idx) = o0;
  *reinterpret_cast<float4*>(hnext + idx + 4) = o1;
}

extern "C" void kernel_launch(void* const* d_in, const int* in_sizes, int n_in,
                              void* d_out, int out_size, void* d_ws, size_t ws_size,
                              hipStream_t stream) {
  (void)in_sizes; (void)n_in; (void)out_size; (void)ws_size;
  const float* x      = (const float*)d_in[0];
  const float* h      = (const float*)d_in[1];
  const float* c      = (const float*)d_in[2];
  const float* Wproj  = (const float*)d_in[3];
  const float* bproj  = (const float*)d_in[4];
  const float* ln_g   = (const float*)d_in[5];
  const float* ln_b   = (const float*)d_in[6];
  const float* Wqkv   = (const float*)d_in[7];
  const float* bqkv   = (const float*)d_in[8];
  const float* Wo     = (const float*)d_in[9];
  const float* bo     = (const float*)d_in[10];
  const float* Wgates = (const float*)d_in[11];
  const float* bgates = (const float*)d_in[12];
  const float* gn_g   = (const float*)d_in[13];
  const float* gn_b   = (const float*)d_in[14];

  float* out = (float*)d_out;
  float* hnext = out;
  float* cnext = out + 16777216;

  char* W = (char*)d_ws;
  ushort* attn = (ushort*)W;                          // 32 MB bf16
  ushort* tbuf = (ushort*)(W + 33554432);             // 32 MB bf16
  size_t off = 67108864;
  ushort* FWp = (ushort*)(W + off); off += 49152;
  ushort* FWq = (ushort*)(W + off); off += 98304;
  ushort* FWo = (ushort*)(W + off); off += 32768;
  ushort* FWg = (ushort*)(W + off); off += 131072;
  float* stA_raw = (float*)(W + off); off += 512;
  float* stB_raw = (float*)(W + off); off += 512;
  float* Sarr    = (float*)(W + off); off += 1536;
  float* Tbarr   = (float*)(W + off); off += 1536;

  hipMemsetAsync(stA_raw, 0, 1024, stream);

  k_prep<<<78, 256, 0, stream>>>(Wproj, Wqkv, Wo, Wgates, ln_g, ln_b, bqkv,
                                 FWp, FWq, FWo, FWg, Sarr, Tbarr);

  k_attn<<<2048, 256, 0, stream>>>(x, h, FWp, bproj, FWq, Sarr, Tbarr,
                                   FWo, bo, attn, stA_raw);
  k_gates<<<4096, 256, 0, stream>>>(attn, stA_raw, gn_g, gn_b, FWg, bgates,
                                    c, cnext, tbuf, stB_raw);
  k_gnout<<<8192, 256, 0, stream>>>(tbuf, stB_raw, gn_g, gn_b, hnext);
}